// Round 20
// baseline (2147.505 us; speedup 1.0000x reference)
//
#include <hip/hip_runtime.h>
#include <hip/hip_bf16.h>

#define T_DIM 1024
#define B_DIM 8
#define C_DIM 512
#define F_DIM 64
#define H_DIM 8
#define CHUNK 32
#define NCHUNK 32

__device__ __forceinline__ float sigmoidf_(float v) { return 1.0f / (1.0f + __expf(-v)); }
__device__ __forceinline__ float geluf_(float v) { return 0.5f * v * (1.0f + erff(v * 0.70710678118654752f)); }
__device__ __forceinline__ float rl_(float v, int l) {
  return __uint_as_float(__builtin_amdgcn_readlane(__float_as_uint(v), l));
}

struct GemmArgs {
  const float* A; const float* W; const float* bias; float* out;
  int M, K, N;
  const float* x; const float* mu; const float* rstd;
  const float* ln_g; const float* ln_b; const float* tl_initial; const float* premix;
  const float* yv; const float* gres;
  float* h2;                 // fp32, lives in d_out until final gemm overwrites
  const float* Wg[6]; const float* bg[6];
};

// ---- A-operand staging split into prefetch (pure loads) + combine (math) ----
struct AFetch {
  float4 v0, v1, v2, v3, v4;
  float s0, s1, s2, s3;
};

// rows r = t*8 + b (output layout is [T,B,C])
template<int MODE_A>
__device__ __forceinline__ AFetch a_fetch(const GemmArgs& g, int r, int c) {
  AFetch f; f.s0 = f.s1 = f.s2 = f.s3 = 0.f;
  if (MODE_A == 0) {
    f.v0 = *(const float4*)&g.A[r * g.K + c];
  } else if (MODE_A == 1) {
    const int b = r & 7, t = r >> 3;
    f.v0 = *(const float4*)&g.x[(b * T_DIM + t) * C_DIM + c];
    f.s0 = g.mu[r]; f.s1 = g.rstd[r];
    if (t > 0) {
      f.v1 = *(const float4*)&g.x[(b * T_DIM + t - 1) * C_DIM + c];
      f.s2 = g.mu[r - 8]; f.s3 = g.rstd[r - 8];
    } else {
      f.v1 = *(const float4*)&g.tl_initial[c];
    }
    f.v2 = *(const float4*)&g.ln_g[c];
    f.v3 = *(const float4*)&g.ln_b[c];
    f.v4 = *(const float4*)&g.premix[c];
  } else {
    f.v0 = *(const float4*)&g.yv[(r >> 3) * C_DIM + c];
    f.v1 = *(const float4*)&g.h2[r * C_DIM + c];
    f.v2 = *(const float4*)&g.gres[c];
  }
  return f;
}

template<int MODE_A>
__device__ __forceinline__ float4 a_combine(const AFetch& f, int r) {
  if (MODE_A == 0) return f.v0;
  float4 o;
  float* op = (float*)&o;
  const float* xa = (const float*)&f.v0;
  const float* xb = (const float*)&f.v1;
  const float* lg = (const float*)&f.v2;
  const float* lb = (const float*)&f.v3;
  const float* pm = (const float*)&f.v4;
  if (MODE_A == 1) {
    const int t = r >> 3;
    #pragma unroll
    for (int q = 0; q < 4; ++q) {
      float h  = (xa[q] - f.s0) * f.s1 * lg[q] + lb[q];
      float xf = (t == 0) ? xb[q] : (xb[q] - f.s2) * f.s3 * lg[q] + lb[q];
      op[q] = h + (xf - h) * pm[q];
    }
    return o;
  }
  #pragma unroll
  for (int q = 0; q < 4; ++q)
    op[q] = xa[q] + xb[q] * lg[q];     // y + h2*gres
  return o;
}

template<int MODE_B>
__device__ __forceinline__ float4 w_fetch(const GemmArgs& g, int kk, int n0, int tc) {
  if (MODE_B == 1)
    return *(const float4*)&g.Wg[blockIdx.y][kk * 64 + (tc << 2)];
  return *(const float4*)&g.W[kk * g.N + n0 + (tc << 2)];
}

// r15-PROVEN GEMM: register double-buffer prefetch; TL2/gating2 run as
// dim3(128,8)=1024 blocks -> TLP hides W latency (r18 lesson: fusion that
// removed that TLP cost 2.8x).
template<int MODE_A, int MODE_B, int EPI>
__global__ __launch_bounds__(256) void gemm_kernel(GemmArgs g) {
  __shared__ float AsT[16][68];  // [k][m], padded
  __shared__ float Bs[16][64];
  const int m0 = blockIdx.x * 64, n0 = blockIdx.y * 64;
  const int tid = threadIdx.x;
  const int tr = tid >> 4, tc = tid & 15;
  const int ai = tid >> 2, aj = (tid & 3) << 2;
  const float scg = (MODE_B == 1 && blockIdx.y == 1) ? 0.125f : 1.0f;
  float acc[4][4] = {};
  AFetch fa = a_fetch<MODE_A>(g, m0 + ai, aj);
  float4 wv = w_fetch<MODE_B>(g, tr, n0, tc);
  for (int k0 = 0; k0 < g.K; k0 += 16) {
    if (k0) __syncthreads();
    const float4 av = a_combine<MODE_A>(fa, m0 + ai);
    AsT[aj + 0][ai] = av.x;
    AsT[aj + 1][ai] = av.y;
    AsT[aj + 2][ai] = av.z;
    AsT[aj + 3][ai] = av.w;
    *(float4*)&Bs[tr][tc << 2] =
        make_float4(wv.x * scg, wv.y * scg, wv.z * scg, wv.w * scg);
    if (k0 + 16 < g.K) {
      fa = a_fetch<MODE_A>(g, m0 + ai, k0 + 16 + aj);
      wv = w_fetch<MODE_B>(g, k0 + 16 + tr, n0, tc);
    }
    __syncthreads();
    #pragma unroll
    for (int kk = 0; kk < 16; ++kk) {
      const float4 a4 = *(const float4*)&AsT[kk][tr << 2];
      const float4 b4 = *(const float4*)&Bs[kk][tc << 2];
      const float avr[4] = {a4.x, a4.y, a4.z, a4.w};
      const float bvr[4] = {b4.x, b4.y, b4.z, b4.w};
      #pragma unroll
      for (int r_ = 0; r_ < 4; ++r_)
        #pragma unroll
        for (int c_ = 0; c_ < 4; ++c_)
          acc[r_][c_] = fmaf(avr[r_], bvr[c_], acc[r_][c_]);
    }
  }
  #pragma unroll
  for (int r_ = 0; r_ < 4; ++r_) {
    const int rr = m0 + (tr << 2) + r_;
    #pragma unroll
    for (int c_ = 0; c_ < 4; ++c_) {
      const int lc = (tc << 2) + c_;      // column within 64-wide tile
      const int cc = n0 + lc;             // global column
      float v = acc[r_][c_];
      if (MODE_B == 1) v += g.bg[blockIdx.y][lc] * scg;
      else if (g.bias) v += g.bias[cc];
      if (EPI == 0) {
        g.out[rr * g.N + cc] = v;
      } else if (EPI == 1) {
        g.out[rr * g.N + cc] = geluf_(v);
      } else if (EPI == 2) {
        float d = sigmoidf_(v);
        const int b = rr & 7, t = rr >> 3;
        float xv = g.x[(b * T_DIM + t) * C_DIM + cc];
        float h = (xv - g.mu[rr]) * g.rstd[rr] * g.ln_g[cc] + g.ln_b[cc];
        float xf;
        if (t == 0) xf = g.tl_initial[cc];
        else {
          float xp = g.x[(b * T_DIM + t - 1) * C_DIM + cc];
          xf = (xp - g.mu[rr - 8]) * g.rstd[rr - 8] * g.ln_g[cc] + g.ln_b[cc];
        }
        g.h2[rr * C_DIM + cc] = h + (xf - h) * d;
      } else {
        float gate = sigmoidf_(v);
        const int b = rr & 7, t = rr >> 3;
        float res = g.x[(b * T_DIM + t) * C_DIM + cc];
        g.out[rr * C_DIM + cc] = res + g.yv[t * C_DIM + cc] * gate;
      }
    }
  }
}

// ln stats + y0 init folded (2048x256 threads == |y| exactly)
__global__ __launch_bounds__(256) void ln_stats_kernel(const float* __restrict__ x,
                                                       float* __restrict__ mu,
                                                       float* __restrict__ rstd,
                                                       const float* __restrict__ bias,
                                                       float* __restrict__ y) {
  const int gid = blockIdx.x * 256 + threadIdx.x;
  y[gid] = bias[gid & (C_DIM - 1)];
  const int row = blockIdx.x * 4 + (threadIdx.x >> 6);  // r = t*8 + b
  const int lane = threadIdx.x & 63;
  const int b = row & 7, t = row >> 3;
  const float* xr = x + (b * T_DIM + t) * C_DIM;
  float4 v0 = *(const float4*)&xr[lane * 8];
  float4 v1 = *(const float4*)&xr[lane * 8 + 4];
  float s  = v0.x + v0.y + v0.z + v0.w + v1.x + v1.y + v1.z + v1.w;
  float s2 = v0.x*v0.x + v0.y*v0.y + v0.z*v0.z + v0.w*v0.w
           + v1.x*v1.x + v1.y*v1.y + v1.z*v1.z + v1.w*v1.w;
  #pragma unroll
  for (int m = 1; m < 64; m <<= 1) { s += __shfl_xor(s, m); s2 += __shfl_xor(s2, m); }
  if (lane == 0) {
    float mean = s * (1.0f / 512.0f);
    float var = s2 * (1.0f / 512.0f) - mean * mean;
    mu[row] = mean;
    rstd[row] = rsqrtf(var + 1e-5f);
  }
}

// ===== Chunk-parallel scan =====
// st_new = st*diag(sg) + (st@a) b^T + c d^T, b prescaled 1/8 at projection.
// PRJ per t: [a|b|c|d|i|sel], 64 each.

// Phase A: per chunk j, P (init I) <- P*M_t ; S (init 0) <- S*M_t + c d^T
// Also zeroes flags[j] for the fused combine+phaseC kernel (deterministic
// per call; runs before combineC in stream order).
__global__ __launch_bounds__(256) void scan_phaseA(const float* __restrict__ PRJ,
                                                   float* __restrict__ chPT,
                                                   float* __restrict__ chS,
                                                   int* __restrict__ flags) {
  const int j = blockIdx.x;
  const int tid = threadIdx.x;
  if (tid == 0) flags[j] = 0;
  const int ri = tid >> 4, ci = tid & 15;
  float Pm[4][4], Sm[4][4];
  #pragma unroll
  for (int r = 0; r < 4; ++r)
    #pragma unroll
    for (int c = 0; c < 4; ++c) {
      Pm[r][c] = (ri * 4 + r == ci * 4 + c) ? 1.0f : 0.0f;
      Sm[r][c] = 0.0f;
    }
  const float* base = PRJ + j * CHUNK * 384;
  float4 pa = *(const float4*)&base[      ci * 4];
  float4 pb = *(const float4*)&base[ 64 + ci * 4];
  float4 pc = *(const float4*)&base[128 + ri * 4];
  float4 pd = *(const float4*)&base[192 + ci * 4];
  float4 pi = *(const float4*)&base[256 + ci * 4];
  for (int s = 0; s < CHUNK; ++s) {
    float4 na = pa, nb = pb, nc2 = pc, nd = pd, ni = pi;
    if (s + 1 < CHUNK) {
      const float* b2 = base + (s + 1) * 384;
      na  = *(const float4*)&b2[      ci * 4];
      nb  = *(const float4*)&b2[ 64 + ci * 4];
      nc2 = *(const float4*)&b2[128 + ri * 4];
      nd  = *(const float4*)&b2[192 + ci * 4];
      ni  = *(const float4*)&b2[256 + ci * 4];
    }
    const float sg[4] = {sigmoidf_(pi.x), sigmoidf_(pi.y), sigmoidf_(pi.z), sigmoidf_(pi.w)};
    const float aa[4] = {pa.x, pa.y, pa.z, pa.w};
    const float bb2[4] = {pb.x, pb.y, pb.z, pb.w};
    const float cv[4] = {pc.x, pc.y, pc.z, pc.w};
    const float dd[4] = {pd.x, pd.y, pd.z, pd.w};
    float rp[4], rs[4];
    #pragma unroll
    for (int r = 0; r < 4; ++r) {
      rp[r] = Pm[r][0]*aa[0] + Pm[r][1]*aa[1] + Pm[r][2]*aa[2] + Pm[r][3]*aa[3];
      rs[r] = Sm[r][0]*aa[0] + Sm[r][1]*aa[1] + Sm[r][2]*aa[2] + Sm[r][3]*aa[3];
    }
    #pragma unroll
    for (int m = 1; m <= 8; m <<= 1) {
      #pragma unroll
      for (int r = 0; r < 4; ++r) {
        rp[r] += __shfl_xor(rp[r], m);
        rs[r] += __shfl_xor(rs[r], m);
      }
    }
    #pragma unroll
    for (int r = 0; r < 4; ++r)
      #pragma unroll
      for (int c = 0; c < 4; ++c) {
        Pm[r][c] = Pm[r][c] * sg[c] + rp[r] * bb2[c];
        Sm[r][c] = Sm[r][c] * sg[c] + rs[r] * bb2[c] + cv[r] * dd[c];
      }
    pa = na; pb = nb; pc = nc2; pd = nd; pi = ni;
  }
  float* cpT = chPT + j * 4096;
  float* cs  = chS + j * 4096;
  #pragma unroll
  for (int c = 0; c < 4; ++c)   // transposed: column (ci*4+c)
    *(float4*)&cpT[(ci*4+c)*64 + ri*4] =
        make_float4(Pm[0][c], Pm[1][c], Pm[2][c], Pm[3][c]);
  #pragma unroll
  for (int r = 0; r < 4; ++r)
    *(float4*)&cs[(ri*4+r)*64 + ci*4] = make_float4(Sm[r][0], Sm[r][1], Sm[r][2], Sm[r][3]);
}

// One chunk-step (rv·P + s) with compile-time readlane indices.
__device__ __forceinline__ float cstep(const float4 (&P)[16], float sv, float rv) {
  float p0 = 0.f, p1 = 0.f, p2 = 0.f, p3 = 0.f;
  #pragma unroll
  for (int q = 0; q < 16; ++q) {
    p0 = fmaf(rl_(rv, q * 4 + 0), P[q].x, p0);
    p1 = fmaf(rl_(rv, q * 4 + 1), P[q].y, p1);
    p2 = fmaf(rl_(rv, q * 4 + 2), P[q].z, p2);
    p3 = fmaf(rl_(rv, q * 4 + 3), P[q].w, p3);
  }
  return sv + ((p0 + p1) + (p2 + p3));
}

// ===== Fused combine + phaseC: 48 blocks, one dispatch =====
// Blocks 0-15 (x4 waves = 64 row-waves): proven single-panel combine; after
// writing chunk j's bnd row, release flags[j] (threadfence + atomicAdd).
// Blocks 16-47: phaseC for chunk j=blk-16; spin on flags[j]==64 then run the
// unchanged phaseC body. 48 blocks on 256 CUs -> all trivially co-resident
// (no occupancy constraint), so the producer always runs; pipeline: phaseC
// chunk 0 starts ~0.4us into combine instead of after a launch gap.
__global__ __launch_bounds__(256) void combineC_kernel(
    const float* __restrict__ st0, const float* __restrict__ chPT,
    const float* __restrict__ chS, float* __restrict__ bnd,
    const float* __restrict__ PRJ, const float* __restrict__ Ow,
    float* __restrict__ y, int* __restrict__ flags) {
  __shared__ float olds[CHUNK][4][64];      // 32 KB
  __shared__ float osT[64][CHUNK + 1];      // padded (8.25 KB)
  const int tid = threadIdx.x;
  if (blockIdx.x < 16) {  // ---- combine: one row per wave ----
    const int lane = tid & 63;
    const int r = blockIdx.x * 4 + (tid >> 6);
    float rv = st0[r * 64 + lane];
    const float* basePT = chPT + lane * 64;   // lane's P^T row
    const float* baseS  = chS + r * 64 + lane;
    float* bndRL = bnd + r * 64 + lane;
    for (int j = 0; j < NCHUNK; ++j) {
      float4 P[16];
      const float* pp = basePT + j * 4096;
      #pragma unroll
      for (int q = 0; q < 16; ++q) P[q] = *(const float4*)&pp[q * 4];
      const float sv = baseS[j * 4096];
      bndRL[j * 4096] = rv;
      __threadfence();                       // wave's bnd store visible device-wide
      if (lane == 0) atomicAdd(&flags[j], 1);
      rv = cstep(P, sv, rv);
    }
    return;
  }
  // ---- phaseC for chunk j ----
  const int j = blockIdx.x - 16;
  if (tid == 0) {
    while (__hip_atomic_load(flags + j, __ATOMIC_ACQUIRE,
                             __HIP_MEMORY_SCOPE_AGENT) < 64) {}
  }
  __syncthreads();
  const int ri = tid >> 4, ci = tid & 15, w = tid >> 6;
  float st[4][4];
  #pragma unroll
  for (int r = 0; r < 4; ++r) {
    const float4 v = *(const float4*)&bnd[j*4096 + (ri*4+r)*64 + ci*4];
    st[r][0] = v.x; st[r][1] = v.y; st[r][2] = v.z; st[r][3] = v.w;
  }
  const float* base = PRJ + j * CHUNK * 384;
  float4 pa = *(const float4*)&base[      ci * 4];
  float4 pb = *(const float4*)&base[ 64 + ci * 4];
  float4 pc = *(const float4*)&base[128 + ri * 4];
  float4 pd = *(const float4*)&base[192 + ci * 4];
  float4 pi = *(const float4*)&base[256 + ci * 4];
  float4 ps = *(const float4*)&base[320 + ri * 4];
  for (int s = 0; s < CHUNK; ++s) {
    float4 na = pa, nb = pb, nc2 = pc, nd = pd, ni = pi, ns = ps;
    if (s + 1 < CHUNK) {
      const float* b2 = base + (s + 1) * 384;
      na  = *(const float4*)&b2[      ci * 4];
      nb  = *(const float4*)&b2[ 64 + ci * 4];
      nc2 = *(const float4*)&b2[128 + ri * 4];
      nd  = *(const float4*)&b2[192 + ci * 4];
      ni  = *(const float4*)&b2[256 + ci * 4];
      ns  = *(const float4*)&b2[320 + ri * 4];
    }
    const float sg[4] = {sigmoidf_(pi.x), sigmoidf_(pi.y), sigmoidf_(pi.z), sigmoidf_(pi.w)};
    const float aa[4] = {pa.x, pa.y, pa.z, pa.w};
    const float bb2[4] = {pb.x, pb.y, pb.z, pb.w};
    const float cv[4] = {pc.x, pc.y, pc.z, pc.w};
    const float dd[4] = {pd.x, pd.y, pd.z, pd.w};
    const float ss[4] = {ps.x, ps.y, ps.z, ps.w};
    float rd[4];
    #pragma unroll
    for (int r = 0; r < 4; ++r)
      rd[r] = st[r][0]*aa[0] + st[r][1]*aa[1] + st[r][2]*aa[2] + st[r][3]*aa[3];
    #pragma unroll
    for (int m = 1; m <= 8; m <<= 1) {
      #pragma unroll
      for (int r = 0; r < 4; ++r) rd[r] += __shfl_xor(rd[r], m);
    }
    float po[4] = {0.f, 0.f, 0.f, 0.f};
    #pragma unroll
    for (int r = 0; r < 4; ++r)
      #pragma unroll
      for (int c = 0; c < 4; ++c) {
        const float nv = st[r][c] * sg[c] + rd[r] * bb2[c] + cv[r] * dd[c];
        st[r][c] = nv;
        po[c] = fmaf(ss[r], nv, po[c]);
      }
    #pragma unroll
    for (int c = 0; c < 4; ++c) {
      po[c] += __shfl_xor(po[c], 16);
      po[c] += __shfl_xor(po[c], 32);
    }
    if ((tid & 48) == 0)
      *(float4*)&olds[s][w][ci * 4] = make_float4(po[0], po[1], po[2], po[3]);
    pa = na; pb = nb; pc = nc2; pd = nd; pi = ni; ps = ns;
  }
  __syncthreads();
  #pragma unroll
  for (int e = 0; e < 8; ++e) {       // cross-wave reduce -> osT[f][t] (padded)
    const int id = tid + 256 * e;
    const int f = id & 63, t = id >> 6;
    osT[f][t] = olds[t][0][f] + olds[t][1][f] + olds[t][2][f] + olds[t][3][f];
  }
  __syncthreads();
  const int c0 = tid << 1;            // 2 output columns per thread
  float2 acc[CHUNK];
  #pragma unroll
  for (int t = 0; t < CHUNK; ++t) acc[t] = make_float2(0.f, 0.f);
  #pragma unroll 1
  for (int fo = 0; fo < 8; ++fo) {    // 8 groups of 8 batched Ow loads
    float2 ow[8];
    #pragma unroll
    for (int q = 0; q < 8; ++q)
      ow[q] = *(const float2*)&Ow[(fo * 8 + q) * C_DIM + c0];
    #pragma unroll
    for (int q = 0; q < 8; ++q) {
      const int f = fo * 8 + q;
      #pragma unroll
      for (int t8 = 0; t8 < 8; ++t8) {
        const float4 ov = *(const float4*)&osT[f][t8 * 4];
        acc[t8*4+0].x = fmaf(ov.x, ow[q].x, acc[t8*4+0].x);
        acc[t8*4+0].y = fmaf(ov.x, ow[q].y, acc[t8*4+0].y);
        acc[t8*4+1].x = fmaf(ov.y, ow[q].x, acc[t8*4+1].x);
        acc[t8*4+1].y = fmaf(ov.y, ow[q].y, acc[t8*4+1].y);
        acc[t8*4+2].x = fmaf(ov.z, ow[q].x, acc[t8*4+2].x);
        acc[t8*4+2].y = fmaf(ov.z, ow[q].y, acc[t8*4+2].y);
        acc[t8*4+3].x = fmaf(ov.w, ow[q].x, acc[t8*4+3].x);
        acc[t8*4+3].y = fmaf(ov.w, ow[q].y, acc[t8*4+3].y);
      }
    }
  }
  #pragma unroll
  for (int t = 0; t < CHUNK; ++t)
    *(float2*)&y[(j * CHUNK + t) * C_DIM + c0] = acc[t];
}

extern "C" void kernel_launch(void* const* d_in, const int* in_sizes, int n_in,
                              void* d_out, int out_size, void* d_ws, size_t ws_size,
                              hipStream_t stream) {
  const float* x       = (const float*)d_in[0];
  const float* ln_g    = (const float*)d_in[1];
  const float* ln_b    = (const float*)d_in[2];
  const float* tl_init = (const float*)d_in[3];
  const float* premix  = (const float*)d_in[4];
  const float* tl_w1   = (const float*)d_in[5];
  const float* tl_b1   = (const float*)d_in[6];
  const float* tl_w2   = (const float*)d_in[7];
  const float* tl_b2   = (const float*)d_in[8];
  const float* bias    = (const float*)d_in[9];
  const float* gres    = (const float*)d_in[10];
  const float* g_w1    = (const float*)d_in[11];
  const float* g_b1    = (const float*)d_in[12];
  const float* g_w2    = (const float*)d_in[13];
  const float* g_b2    = (const float*)d_in[14];
  const float* dn_init = (const float*)d_in[15];
  const float* A_w     = (const float*)d_in[16];
  const float* A_b     = (const float*)d_in[17];
  const float* B_w     = (const float*)d_in[18];
  const float* B_b     = (const float*)d_in[19];
  const float* C_w     = (const float*)d_in[20];
  const float* C_b     = (const float*)d_in[21];
  const float* D_w     = (const float*)d_in[22];
  const float* D_b     = (const float*)d_in[23];
  const float* I_w     = (const float*)d_in[24];
  const float* I_b     = (const float*)d_in[25];
  const float* S_w     = (const float*)d_in[26];
  const float* S_b     = (const float*)d_in[27];
  const float* O_w     = (const float*)d_in[28];

  // ws ~6.6 MB. h2 (fp32, 8192x512 = out_size) lives in d_out until the final
  // gemm overwrites it (only gating gemm1 reads it; same stream).
  float* ws      = (float*)d_ws;
  float* mu      = ws;                  // 8192
  float* rstd    = mu + 8192;           // 8192
  float* hidden1 = rstd + 8192;         // 524288 (8192 x 64; reused by gating)
  float* y       = hidden1 + 524288;    // 524288 (1024 x 512)
  float* PRJ     = y + 524288;          // 393216 (1024 x 384)
  float* chPT    = PRJ + 393216;        // 131072 (32 x 64 x 64, transposed)
  float* chS     = chPT + 131072;       // 131072
  float* bnd     = chS + 131072;        // 131072
  int*   flags   = (int*)(bnd + 131072);// 32 ints (zeroed by phaseA each call)
  float* h2      = (float*)d_out;       // 4194304 fp32 == full d_out

  ln_stats_kernel<<<2048, 256, 0, stream>>>(x, mu, rstd, bias, y);

  GemmArgs ga = {};
  ga.x = x; ga.mu = mu; ga.rstd = rstd; ga.ln_g = ln_g; ga.ln_b = ln_b;
  ga.tl_initial = tl_init; ga.premix = premix; ga.gres = gres; ga.h2 = h2;

  {  // TokenLerp MLP layer 1: hidden1 = gelu(pm @ tl_w1 + tl_b1)
    GemmArgs g = ga; g.W = tl_w1; g.bias = tl_b1; g.out = hidden1;
    g.M = 8192; g.K = 512; g.N = 64;
    gemm_kernel<1, 0, 1><<<dim3(128, 1), 256, 0, stream>>>(g);
  }
  {  // TokenLerp layer 2 -> h2 (fp32, stored in d_out)
    GemmArgs g = ga; g.A = hidden1; g.W = tl_w2; g.bias = tl_b2;
    g.M = 8192; g.K = 64; g.N = 512;
    gemm_kernel<0, 0, 2><<<dim3(128, 8), 256, 0, stream>>>(g);
  }

  for (int k = 0; k < H_DIM; ++k) {
    {  // fused 6-way projection: PRJ[t, grp*64+f] = y @ {A,B/8,C,D,I,S}_w[k] + bias
      GemmArgs g = ga; g.A = y; g.out = PRJ; g.M = 1024; g.K = 512; g.N = 384;
      const int woff = k * C_DIM * F_DIM, boff = k * F_DIM;
      g.Wg[0] = A_w + woff; g.Wg[1] = B_w + woff; g.Wg[2] = C_w + woff;
      g.Wg[3] = D_w + woff; g.Wg[4] = I_w + woff; g.Wg[5] = S_w + woff;
      g.bg[0] = A_b + boff; g.bg[1] = B_b + boff; g.bg[2] = C_b + boff;
      g.bg[3] = D_b + boff; g.bg[4] = I_b + boff; g.bg[5] = S_b + boff;
      gemm_kernel<0, 1, 0><<<dim3(16, 6), 256, 0, stream>>>(g);
    }
    scan_phaseA<<<NCHUNK, 256, 0, stream>>>(PRJ, chPT, chS, flags);
    combineC_kernel<<<48, 256, 0, stream>>>(dn_init + k * 4096, chPT, chS, bnd,
                                            PRJ, O_w + k * F_DIM * C_DIM, y, flags);
  }

  {  // gating layer 1: hidden1 = gelu((y + h2*gres) @ g_w1 + g_b1)
    GemmArgs g = ga; g.yv = y; g.W = g_w1; g.bias = g_b1; g.out = hidden1;
    g.M = 8192; g.K = 512; g.N = 64;
    gemm_kernel<2, 0, 1><<<dim3(128, 1), 256, 0, stream>>>(g);
  }
  {  // gating layer 2 + final output (fp32): out = x^T + y*sigmoid(...)
    GemmArgs g = ga; g.yv = y; g.A = hidden1; g.W = g_w2; g.bias = g_b2;
    g.out = (float*)d_out; g.M = 8192; g.K = 64; g.N = 512;
    gemm_kernel<0, 0, 3><<<dim3(128, 8), 256, 0, stream>>>(g);
  }
}

// Round 21
// 1009.718 us; speedup vs baseline: 2.1268x; 2.1268x over previous
//
#include <hip/hip_runtime.h>
#include <hip/hip_bf16.h>

#define T_DIM 1024
#define B_DIM 8
#define C_DIM 512
#define F_DIM 64
#define H_DIM 8
#define CHUNK 32
#define NCHUNK 32

__device__ __forceinline__ float sigmoidf_(float v) { return 1.0f / (1.0f + __expf(-v)); }
__device__ __forceinline__ float geluf_(float v) { return 0.5f * v * (1.0f + erff(v * 0.70710678118654752f)); }
__device__ __forceinline__ float rl_(float v, int l) {
  return __uint_as_float(__builtin_amdgcn_readlane(__float_as_uint(v), l));
}

struct GemmArgs {
  const float* A; const float* W; const float* bias; float* out;
  int M, K, N;
  const float* x; const float* mu; const float* rstd;
  const float* ln_g; const float* ln_b; const float* tl_initial; const float* premix;
  const float* yv; const float* gres;
  float* h2;                 // fp32, lives in d_out until final gemm overwrites
  const float* Wg[6]; const float* bg[6];
};

// ---- A-operand staging split into prefetch (pure loads) + combine (math) ----
struct AFetch {
  float4 v0, v1, v2, v3, v4;
  float s0, s1, s2, s3;
};

// rows r = t*8 + b (output layout is [T,B,C])
template<int MODE_A>
__device__ __forceinline__ AFetch a_fetch(const GemmArgs& g, int r, int c) {
  AFetch f; f.s0 = f.s1 = f.s2 = f.s3 = 0.f;
  if (MODE_A == 0) {
    f.v0 = *(const float4*)&g.A[r * g.K + c];
  } else if (MODE_A == 1) {
    const int b = r & 7, t = r >> 3;
    f.v0 = *(const float4*)&g.x[(b * T_DIM + t) * C_DIM + c];
    f.s0 = g.mu[r]; f.s1 = g.rstd[r];
    if (t > 0) {
      f.v1 = *(const float4*)&g.x[(b * T_DIM + t - 1) * C_DIM + c];
      f.s2 = g.mu[r - 8]; f.s3 = g.rstd[r - 8];
    } else {
      f.v1 = *(const float4*)&g.tl_initial[c];
    }
    f.v2 = *(const float4*)&g.ln_g[c];
    f.v3 = *(const float4*)&g.ln_b[c];
    f.v4 = *(const float4*)&g.premix[c];
  } else {
    f.v0 = *(const float4*)&g.yv[(r >> 3) * C_DIM + c];
    f.v1 = *(const float4*)&g.h2[r * C_DIM + c];
    f.v2 = *(const float4*)&g.gres[c];
  }
  return f;
}

template<int MODE_A>
__device__ __forceinline__ float4 a_combine(const AFetch& f, int r) {
  if (MODE_A == 0) return f.v0;
  float4 o;
  float* op = (float*)&o;
  const float* xa = (const float*)&f.v0;
  const float* xb = (const float*)&f.v1;
  const float* lg = (const float*)&f.v2;
  const float* lb = (const float*)&f.v3;
  const float* pm = (const float*)&f.v4;
  if (MODE_A == 1) {
    const int t = r >> 3;
    #pragma unroll
    for (int q = 0; q < 4; ++q) {
      float h  = (xa[q] - f.s0) * f.s1 * lg[q] + lb[q];
      float xf = (t == 0) ? xb[q] : (xb[q] - f.s2) * f.s3 * lg[q] + lb[q];
      op[q] = h + (xf - h) * pm[q];
    }
    return o;
  }
  #pragma unroll
  for (int q = 0; q < 4; ++q)
    op[q] = xa[q] + xb[q] * lg[q];     // y + h2*gres
  return o;
}

template<int MODE_B>
__device__ __forceinline__ float4 w_fetch(const GemmArgs& g, int kk, int n0, int tc) {
  if (MODE_B == 1)
    return *(const float4*)&g.Wg[blockIdx.y][kk * 64 + (tc << 2)];
  return *(const float4*)&g.W[kk * g.N + n0 + (tc << 2)];
}

// r15-PROVEN GEMM: register double-buffer prefetch; TL2/gating2 run as
// dim3(128,8)=1024 blocks -> TLP hides W latency.
template<int MODE_A, int MODE_B, int EPI>
__global__ __launch_bounds__(256) void gemm_kernel(GemmArgs g) {
  __shared__ float AsT[16][68];  // [k][m], padded
  __shared__ float Bs[16][64];
  const int m0 = blockIdx.x * 64, n0 = blockIdx.y * 64;
  const int tid = threadIdx.x;
  const int tr = tid >> 4, tc = tid & 15;
  const int ai = tid >> 2, aj = (tid & 3) << 2;
  const float scg = (MODE_B == 1 && blockIdx.y == 1) ? 0.125f : 1.0f;
  float acc[4][4] = {};
  AFetch fa = a_fetch<MODE_A>(g, m0 + ai, aj);
  float4 wv = w_fetch<MODE_B>(g, tr, n0, tc);
  for (int k0 = 0; k0 < g.K; k0 += 16) {
    if (k0) __syncthreads();
    const float4 av = a_combine<MODE_A>(fa, m0 + ai);
    AsT[aj + 0][ai] = av.x;
    AsT[aj + 1][ai] = av.y;
    AsT[aj + 2][ai] = av.z;
    AsT[aj + 3][ai] = av.w;
    *(float4*)&Bs[tr][tc << 2] =
        make_float4(wv.x * scg, wv.y * scg, wv.z * scg, wv.w * scg);
    if (k0 + 16 < g.K) {
      fa = a_fetch<MODE_A>(g, m0 + ai, k0 + 16 + aj);
      wv = w_fetch<MODE_B>(g, k0 + 16 + tr, n0, tc);
    }
    __syncthreads();
    #pragma unroll
    for (int kk = 0; kk < 16; ++kk) {
      const float4 a4 = *(const float4*)&AsT[kk][tr << 2];
      const float4 b4 = *(const float4*)&Bs[kk][tc << 2];
      const float avr[4] = {a4.x, a4.y, a4.z, a4.w};
      const float bvr[4] = {b4.x, b4.y, b4.z, b4.w};
      #pragma unroll
      for (int r_ = 0; r_ < 4; ++r_)
        #pragma unroll
        for (int c_ = 0; c_ < 4; ++c_)
          acc[r_][c_] = fmaf(avr[r_], bvr[c_], acc[r_][c_]);
    }
  }
  #pragma unroll
  for (int r_ = 0; r_ < 4; ++r_) {
    const int rr = m0 + (tr << 2) + r_;
    #pragma unroll
    for (int c_ = 0; c_ < 4; ++c_) {
      const int lc = (tc << 2) + c_;      // column within 64-wide tile
      const int cc = n0 + lc;             // global column
      float v = acc[r_][c_];
      if (MODE_B == 1) v += g.bg[blockIdx.y][lc] * scg;
      else if (g.bias) v += g.bias[cc];
      if (EPI == 0) {
        g.out[rr * g.N + cc] = v;
      } else if (EPI == 1) {
        g.out[rr * g.N + cc] = geluf_(v);
      } else if (EPI == 2) {
        float d = sigmoidf_(v);
        const int b = rr & 7, t = rr >> 3;
        float xv = g.x[(b * T_DIM + t) * C_DIM + cc];
        float h = (xv - g.mu[rr]) * g.rstd[rr] * g.ln_g[cc] + g.ln_b[cc];
        float xf;
        if (t == 0) xf = g.tl_initial[cc];
        else {
          float xp = g.x[(b * T_DIM + t - 1) * C_DIM + cc];
          xf = (xp - g.mu[rr - 8]) * g.rstd[rr - 8] * g.ln_g[cc] + g.ln_b[cc];
        }
        g.h2[rr * C_DIM + cc] = h + (xf - h) * d;
      } else {
        float gate = sigmoidf_(v);
        const int b = rr & 7, t = rr >> 3;
        float res = g.x[(b * T_DIM + t) * C_DIM + cc];
        g.out[rr * C_DIM + cc] = res + g.yv[t * C_DIM + cc] * gate;
      }
    }
  }
}

// ln stats + y0 init folded (2048x256 threads == |y| exactly)
__global__ __launch_bounds__(256) void ln_stats_kernel(const float* __restrict__ x,
                                                       float* __restrict__ mu,
                                                       float* __restrict__ rstd,
                                                       const float* __restrict__ bias,
                                                       float* __restrict__ y) {
  const int gid = blockIdx.x * 256 + threadIdx.x;
  y[gid] = bias[gid & (C_DIM - 1)];
  const int row = blockIdx.x * 4 + (threadIdx.x >> 6);  // r = t*8 + b
  const int lane = threadIdx.x & 63;
  const int b = row & 7, t = row >> 3;
  const float* xr = x + (b * T_DIM + t) * C_DIM;
  float4 v0 = *(const float4*)&xr[lane * 8];
  float4 v1 = *(const float4*)&xr[lane * 8 + 4];
  float s  = v0.x + v0.y + v0.z + v0.w + v1.x + v1.y + v1.z + v1.w;
  float s2 = v0.x*v0.x + v0.y*v0.y + v0.z*v0.z + v0.w*v0.w
           + v1.x*v1.x + v1.y*v1.y + v1.z*v1.z + v1.w*v1.w;
  #pragma unroll
  for (int m = 1; m < 64; m <<= 1) { s += __shfl_xor(s, m); s2 += __shfl_xor(s2, m); }
  if (lane == 0) {
    float mean = s * (1.0f / 512.0f);
    float var = s2 * (1.0f / 512.0f) - mean * mean;
    mu[row] = mean;
    rstd[row] = rsqrtf(var + 1e-5f);
  }
}

// ===== Chunk-parallel scan =====
// st_new = st*diag(sg) + (st@a) b^T + c d^T, b prescaled 1/8 at projection.
// PRJ per t: [a|b|c|d|i|sel], 64 each.

// Phase A with DEPTH-2 register pipeline (r20 diagnosis: per-step time was
// dominated by the ~600cy PRJ load latency vs ~300cy compute; two named
// 5-float4 buffer sets (+20 VGPR, ~100 total -- far from the r12/r13 spill
// regime) give each load ~2 compute blocks to land).
__global__ __launch_bounds__(256) void scan_phaseA(const float* __restrict__ PRJ,
                                                   float* __restrict__ chPT,
                                                   float* __restrict__ chS) {
  const int j = blockIdx.x;
  const int tid = threadIdx.x;
  const int ri = tid >> 4, ci = tid & 15;
  float Pm[4][4], Sm[4][4];
  #pragma unroll
  for (int r = 0; r < 4; ++r)
    #pragma unroll
    for (int c = 0; c < 4; ++c) {
      Pm[r][c] = (ri * 4 + r == ci * 4 + c) ? 1.0f : 0.0f;
      Sm[r][c] = 0.0f;
    }
  const float* base = PRJ + j * CHUNK * 384;

  auto stepA = [&](const float4& pa, const float4& pb, const float4& pc,
                   const float4& pd, const float4& pi) {
    const float sg[4] = {sigmoidf_(pi.x), sigmoidf_(pi.y), sigmoidf_(pi.z), sigmoidf_(pi.w)};
    const float aa[4] = {pa.x, pa.y, pa.z, pa.w};
    const float bb2[4] = {pb.x, pb.y, pb.z, pb.w};
    const float cv[4] = {pc.x, pc.y, pc.z, pc.w};
    const float dd[4] = {pd.x, pd.y, pd.z, pd.w};
    float rp[4], rs[4];
    #pragma unroll
    for (int r = 0; r < 4; ++r) {
      rp[r] = Pm[r][0]*aa[0] + Pm[r][1]*aa[1] + Pm[r][2]*aa[2] + Pm[r][3]*aa[3];
      rs[r] = Sm[r][0]*aa[0] + Sm[r][1]*aa[1] + Sm[r][2]*aa[2] + Sm[r][3]*aa[3];
    }
    #pragma unroll
    for (int m = 1; m <= 8; m <<= 1) {
      #pragma unroll
      for (int r = 0; r < 4; ++r) {
        rp[r] += __shfl_xor(rp[r], m);
        rs[r] += __shfl_xor(rs[r], m);
      }
    }
    #pragma unroll
    for (int r = 0; r < 4; ++r)
      #pragma unroll
      for (int c = 0; c < 4; ++c) {
        Pm[r][c] = Pm[r][c] * sg[c] + rp[r] * bb2[c];
        Sm[r][c] = Sm[r][c] * sg[c] + rs[r] * bb2[c] + cv[r] * dd[c];
      }
  };

  float4 a0, b0, c0, d0, i0, a1, b1, c1, d1, i1;
  {
    const float* p0 = base;
    a0 = *(const float4*)&p0[      ci * 4]; b0 = *(const float4*)&p0[ 64 + ci * 4];
    c0 = *(const float4*)&p0[128 + ri * 4]; d0 = *(const float4*)&p0[192 + ci * 4];
    i0 = *(const float4*)&p0[256 + ci * 4];
    const float* p1 = base + 384;
    a1 = *(const float4*)&p1[      ci * 4]; b1 = *(const float4*)&p1[ 64 + ci * 4];
    c1 = *(const float4*)&p1[128 + ri * 4]; d1 = *(const float4*)&p1[192 + ci * 4];
    i1 = *(const float4*)&p1[256 + ci * 4];
  }
  for (int s = 0; s < CHUNK; s += 2) {
    stepA(a0, b0, c0, d0, i0);
    if (s + 2 < CHUNK) {
      const float* p2 = base + (s + 2) * 384;
      a0 = *(const float4*)&p2[      ci * 4]; b0 = *(const float4*)&p2[ 64 + ci * 4];
      c0 = *(const float4*)&p2[128 + ri * 4]; d0 = *(const float4*)&p2[192 + ci * 4];
      i0 = *(const float4*)&p2[256 + ci * 4];
    }
    stepA(a1, b1, c1, d1, i1);
    if (s + 3 < CHUNK) {
      const float* p3 = base + (s + 3) * 384;
      a1 = *(const float4*)&p3[      ci * 4]; b1 = *(const float4*)&p3[ 64 + ci * 4];
      c1 = *(const float4*)&p3[128 + ri * 4]; d1 = *(const float4*)&p3[192 + ci * 4];
      i1 = *(const float4*)&p3[256 + ci * 4];
    }
  }
  float* cpT = chPT + j * 4096;
  float* cs  = chS + j * 4096;
  #pragma unroll
  for (int c = 0; c < 4; ++c)   // transposed: column (ci*4+c)
    *(float4*)&cpT[(ci*4+c)*64 + ri*4] =
        make_float4(Pm[0][c], Pm[1][c], Pm[2][c], Pm[3][c]);
  #pragma unroll
  for (int r = 0; r < 4; ++r)
    *(float4*)&cs[(ri*4+r)*64 + ci*4] = make_float4(Sm[r][0], Sm[r][1], Sm[r][2], Sm[r][3]);
}

// One chunk-step (rv·P + s) with compile-time readlane indices.
__device__ __forceinline__ float cstep(const float4 (&P)[16], float sv, float rv) {
  float p0 = 0.f, p1 = 0.f, p2 = 0.f, p3 = 0.f;
  #pragma unroll
  for (int q = 0; q < 16; ++q) {
    p0 = fmaf(rl_(rv, q * 4 + 0), P[q].x, p0);
    p1 = fmaf(rl_(rv, q * 4 + 1), P[q].y, p1);
    p2 = fmaf(rl_(rv, q * 4 + 2), P[q].z, p2);
    p3 = fmaf(rl_(rv, q * 4 + 3), P[q].w, p3);
  }
  return sv + ((p0 + p1) + (p2 + p3));
}

// Phase B (row-parallel): 64 blocks x 1 wave, one row per wave, lane = column.
// Single register panel (multi-panel pipelines spill to scratch: r12/r13).
__global__ __launch_bounds__(64) void scan_combine(const float* __restrict__ st0,
                                                   const float* __restrict__ chPT,
                                                   const float* __restrict__ chS,
                                                   float* __restrict__ bnd) {
  const int lane = threadIdx.x;          // column c
  const int r = blockIdx.x;              // row 0..63
  float rv = st0[r * 64 + lane];
  const float* basePT = chPT + lane * 64;   // lane's P^T row
  const float* baseS  = chS + r * 64 + lane;
  float* bndRL = bnd + r * 64 + lane;
  for (int j = 0; j < NCHUNK; ++j) {
    float4 P[16];
    const float* pp = basePT + j * 4096;
    #pragma unroll
    for (int q = 0; q < 16; ++q) P[q] = *(const float4*)&pp[q * 4];
    const float sv = baseS[j * 4096];
    bndRL[j * 4096] = rv;
    rv = cstep(P, sv, rv);
  }
}

// Phase C (+ fused y-GEMM) with DEPTH-2 prefetch on the PRJ stream (same
// rationale as phaseA; two 6-float4 sets = +24 VGPR during the scan loop).
__global__ __launch_bounds__(256) void scan_phaseC(const float* __restrict__ PRJ,
                                                   const float* __restrict__ bnd,
                                                   const float* __restrict__ Ow,
                                                   float* __restrict__ y) {
  __shared__ float olds[CHUNK][4][64];      // 32 KB
  __shared__ float osT[64][CHUNK + 1];      // padded (8.25 KB)
  const int j = blockIdx.x;
  const int tid = threadIdx.x;
  const int ri = tid >> 4, ci = tid & 15, w = tid >> 6;
  float st[4][4];
  #pragma unroll
  for (int r = 0; r < 4; ++r) {
    const float4 v = *(const float4*)&bnd[j*4096 + (ri*4+r)*64 + ci*4];
    st[r][0] = v.x; st[r][1] = v.y; st[r][2] = v.z; st[r][3] = v.w;
  }
  const float* base = PRJ + j * CHUNK * 384;

  auto stepC = [&](int s, const float4& pa, const float4& pb, const float4& pc,
                   const float4& pd, const float4& pi, const float4& ps) {
    const float sg[4] = {sigmoidf_(pi.x), sigmoidf_(pi.y), sigmoidf_(pi.z), sigmoidf_(pi.w)};
    const float aa[4] = {pa.x, pa.y, pa.z, pa.w};
    const float bb2[4] = {pb.x, pb.y, pb.z, pb.w};
    const float cv[4] = {pc.x, pc.y, pc.z, pc.w};
    const float dd[4] = {pd.x, pd.y, pd.z, pd.w};
    const float ss[4] = {ps.x, ps.y, ps.z, ps.w};
    float rd[4];
    #pragma unroll
    for (int r = 0; r < 4; ++r)
      rd[r] = st[r][0]*aa[0] + st[r][1]*aa[1] + st[r][2]*aa[2] + st[r][3]*aa[3];
    #pragma unroll
    for (int m = 1; m <= 8; m <<= 1) {
      #pragma unroll
      for (int r = 0; r < 4; ++r) rd[r] += __shfl_xor(rd[r], m);
    }
    float po[4] = {0.f, 0.f, 0.f, 0.f};
    #pragma unroll
    for (int r = 0; r < 4; ++r)
      #pragma unroll
      for (int c = 0; c < 4; ++c) {
        const float nv = st[r][c] * sg[c] + rd[r] * bb2[c] + cv[r] * dd[c];
        st[r][c] = nv;
        po[c] = fmaf(ss[r], nv, po[c]);
      }
    #pragma unroll
    for (int c = 0; c < 4; ++c) {
      po[c] += __shfl_xor(po[c], 16);
      po[c] += __shfl_xor(po[c], 32);
    }
    if ((tid & 48) == 0)
      *(float4*)&olds[s][w][ci * 4] = make_float4(po[0], po[1], po[2], po[3]);
  };

  float4 a0, b0, c0, d0, i0, s0, a1, b1, c1, d1, i1, s1;
  {
    const float* p0 = base;
    a0 = *(const float4*)&p0[      ci * 4]; b0 = *(const float4*)&p0[ 64 + ci * 4];
    c0 = *(const float4*)&p0[128 + ri * 4]; d0 = *(const float4*)&p0[192 + ci * 4];
    i0 = *(const float4*)&p0[256 + ci * 4]; s0 = *(const float4*)&p0[320 + ri * 4];
    const float* p1 = base + 384;
    a1 = *(const float4*)&p1[      ci * 4]; b1 = *(const float4*)&p1[ 64 + ci * 4];
    c1 = *(const float4*)&p1[128 + ri * 4]; d1 = *(const float4*)&p1[192 + ci * 4];
    i1 = *(const float4*)&p1[256 + ci * 4]; s1 = *(const float4*)&p1[320 + ri * 4];
  }
  for (int s = 0; s < CHUNK; s += 2) {
    stepC(s, a0, b0, c0, d0, i0, s0);
    if (s + 2 < CHUNK) {
      const float* p2 = base + (s + 2) * 384;
      a0 = *(const float4*)&p2[      ci * 4]; b0 = *(const float4*)&p2[ 64 + ci * 4];
      c0 = *(const float4*)&p2[128 + ri * 4]; d0 = *(const float4*)&p2[192 + ci * 4];
      i0 = *(const float4*)&p2[256 + ci * 4]; s0 = *(const float4*)&p2[320 + ri * 4];
    }
    stepC(s + 1, a1, b1, c1, d1, i1, s1);
    if (s + 3 < CHUNK) {
      const float* p3 = base + (s + 3) * 384;
      a1 = *(const float4*)&p3[      ci * 4]; b1 = *(const float4*)&p3[ 64 + ci * 4];
      c1 = *(const float4*)&p3[128 + ri * 4]; d1 = *(const float4*)&p3[192 + ci * 4];
      i1 = *(const float4*)&p3[256 + ci * 4]; s1 = *(const float4*)&p3[320 + ri * 4];
    }
  }
  __syncthreads();
  #pragma unroll
  for (int e = 0; e < 8; ++e) {       // cross-wave reduce -> osT[f][t] (padded)
    const int id = tid + 256 * e;
    const int f = id & 63, t = id >> 6;
    osT[f][t] = olds[t][0][f] + olds[t][1][f] + olds[t][2][f] + olds[t][3][f];
  }
  __syncthreads();
  const int c0v = tid << 1;           // 2 output columns per thread
  float2 acc[CHUNK];
  #pragma unroll
  for (int t = 0; t < CHUNK; ++t) acc[t] = make_float2(0.f, 0.f);
  #pragma unroll 1
  for (int fo = 0; fo < 8; ++fo) {    // 8 groups of 8 batched Ow loads
    float2 ow[8];
    #pragma unroll
    for (int q = 0; q < 8; ++q)
      ow[q] = *(const float2*)&Ow[(fo * 8 + q) * C_DIM + c0v];
    #pragma unroll
    for (int q = 0; q < 8; ++q) {
      const int f = fo * 8 + q;
      #pragma unroll
      for (int t8 = 0; t8 < 8; ++t8) {
        const float4 ov = *(const float4*)&osT[f][t8 * 4];
        acc[t8*4+0].x = fmaf(ov.x, ow[q].x, acc[t8*4+0].x);
        acc[t8*4+0].y = fmaf(ov.x, ow[q].y, acc[t8*4+0].y);
        acc[t8*4+1].x = fmaf(ov.y, ow[q].x, acc[t8*4+1].x);
        acc[t8*4+1].y = fmaf(ov.y, ow[q].y, acc[t8*4+1].y);
        acc[t8*4+2].x = fmaf(ov.z, ow[q].x, acc[t8*4+2].x);
        acc[t8*4+2].y = fmaf(ov.z, ow[q].y, acc[t8*4+2].y);
        acc[t8*4+3].x = fmaf(ov.w, ow[q].x, acc[t8*4+3].x);
        acc[t8*4+3].y = fmaf(ov.w, ow[q].y, acc[t8*4+3].y);
      }
    }
  }
  #pragma unroll
  for (int t = 0; t < CHUNK; ++t)
    *(float2*)&y[(j * CHUNK + t) * C_DIM + c0v] = acc[t];
}

extern "C" void kernel_launch(void* const* d_in, const int* in_sizes, int n_in,
                              void* d_out, int out_size, void* d_ws, size_t ws_size,
                              hipStream_t stream) {
  const float* x       = (const float*)d_in[0];
  const float* ln_g    = (const float*)d_in[1];
  const float* ln_b    = (const float*)d_in[2];
  const float* tl_init = (const float*)d_in[3];
  const float* premix  = (const float*)d_in[4];
  const float* tl_w1   = (const float*)d_in[5];
  const float* tl_b1   = (const float*)d_in[6];
  const float* tl_w2   = (const float*)d_in[7];
  const float* tl_b2   = (const float*)d_in[8];
  const float* bias    = (const float*)d_in[9];
  const float* gres    = (const float*)d_in[10];
  const float* g_w1    = (const float*)d_in[11];
  const float* g_b1    = (const float*)d_in[12];
  const float* g_w2    = (const float*)d_in[13];
  const float* g_b2    = (const float*)d_in[14];
  const float* dn_init = (const float*)d_in[15];
  const float* A_w     = (const float*)d_in[16];
  const float* A_b     = (const float*)d_in[17];
  const float* B_w     = (const float*)d_in[18];
  const float* B_b     = (const float*)d_in[19];
  const float* C_w     = (const float*)d_in[20];
  const float* C_b     = (const float*)d_in[21];
  const float* D_w     = (const float*)d_in[22];
  const float* D_b     = (const float*)d_in[23];
  const float* I_w     = (const float*)d_in[24];
  const float* I_b     = (const float*)d_in[25];
  const float* S_w     = (const float*)d_in[26];
  const float* S_b     = (const float*)d_in[27];
  const float* O_w     = (const float*)d_in[28];

  // ws ~6.6 MB. h2 (fp32, 8192x512 = out_size) lives in d_out until the final
  // gemm overwrites it (only gating gemm1 reads it; same stream).
  float* ws      = (float*)d_ws;
  float* mu      = ws;                  // 8192
  float* rstd    = mu + 8192;           // 8192
  float* hidden1 = rstd + 8192;         // 524288 (8192 x 64; reused by gating)
  float* y       = hidden1 + 524288;    // 524288 (1024 x 512)
  float* PRJ     = y + 524288;          // 393216 (1024 x 384)
  float* chPT    = PRJ + 393216;        // 131072 (32 x 64 x 64, transposed)
  float* chS     = chPT + 131072;       // 131072
  float* bnd     = chS + 131072;        // 131072
  float* h2      = (float*)d_out;       // 4194304 fp32 == full d_out

  ln_stats_kernel<<<2048, 256, 0, stream>>>(x, mu, rstd, bias, y);

  GemmArgs ga = {};
  ga.x = x; ga.mu = mu; ga.rstd = rstd; ga.ln_g = ln_g; ga.ln_b = ln_b;
  ga.tl_initial = tl_init; ga.premix = premix; ga.gres = gres; ga.h2 = h2;

  {  // TokenLerp MLP layer 1: hidden1 = gelu(pm @ tl_w1 + tl_b1)
    GemmArgs g = ga; g.W = tl_w1; g.bias = tl_b1; g.out = hidden1;
    g.M = 8192; g.K = 512; g.N = 64;
    gemm_kernel<1, 0, 1><<<dim3(128, 1), 256, 0, stream>>>(g);
  }
  {  // TokenLerp layer 2 -> h2 (fp32, stored in d_out)
    GemmArgs g = ga; g.A = hidden1; g.W = tl_w2; g.bias = tl_b2;
    g.M = 8192; g.K = 64; g.N = 512;
    gemm_kernel<0, 0, 2><<<dim3(128, 8), 256, 0, stream>>>(g);
  }

  for (int k = 0; k < H_DIM; ++k) {
    {  // fused 6-way projection: PRJ[t, grp*64+f] = y @ {A,B/8,C,D,I,S}_w[k] + bias
      GemmArgs g = ga; g.A = y; g.out = PRJ; g.M = 1024; g.K = 512; g.N = 384;
      const int woff = k * C_DIM * F_DIM, boff = k * F_DIM;
      g.Wg[0] = A_w + woff; g.Wg[1] = B_w + woff; g.Wg[2] = C_w + woff;
      g.Wg[3] = D_w + woff; g.Wg[4] = I_w + woff; g.Wg[5] = S_w + woff;
      g.bg[0] = A_b + boff; g.bg[1] = B_b + boff; g.bg[2] = C_b + boff;
      g.bg[3] = D_b + boff; g.bg[4] = I_b + boff; g.bg[5] = S_b + boff;
      gemm_kernel<0, 1, 0><<<dim3(16, 6), 256, 0, stream>>>(g);
    }
    scan_phaseA<<<NCHUNK, 256, 0, stream>>>(PRJ, chPT, chS);
    scan_combine<<<64, 64, 0, stream>>>(dn_init + k * 4096, chPT, chS, bnd);
    scan_phaseC<<<NCHUNK, 256, 0, stream>>>(PRJ, bnd, O_w + k * F_DIM * C_DIM, y);
  }

  {  // gating layer 1: hidden1 = gelu((y + h2*gres) @ g_w1 + g_b1)
    GemmArgs g = ga; g.yv = y; g.W = g_w1; g.bias = g_b1; g.out = hidden1;
    g.M = 8192; g.K = 512; g.N = 64;
    gemm_kernel<2, 0, 1><<<dim3(128, 1), 256, 0, stream>>>(g);
  }
  {  // gating layer 2 + final output (fp32): out = x^T + y*sigmoid(...)
    GemmArgs g = ga; g.yv = y; g.A = hidden1; g.W = g_w2; g.bias = g_b2;
    g.out = (float*)d_out; g.M = 8192; g.K = 64; g.N = 512;
    gemm_kernel<0, 0, 3><<<dim3(128, 8), 256, 0, stream>>>(g);
  }
}

// Round 22
// 986.741 us; speedup vs baseline: 2.1764x; 1.0233x over previous
//
#include <hip/hip_runtime.h>
#include <hip/hip_bf16.h>

#define T_DIM 1024
#define B_DIM 8
#define C_DIM 512
#define F_DIM 64
#define H_DIM 8
#define CHUNK 16
#define NCHUNK 64

__device__ __forceinline__ float sigmoidf_(float v) { return 1.0f / (1.0f + __expf(-v)); }
__device__ __forceinline__ float geluf_(float v) { return 0.5f * v * (1.0f + erff(v * 0.70710678118654752f)); }
__device__ __forceinline__ float rl_(float v, int l) {
  return __uint_as_float(__builtin_amdgcn_readlane(__float_as_uint(v), l));
}

struct GemmArgs {
  const float* A; const float* W; const float* bias; float* out;
  int M, K, N;
  const float* x; const float* mu; const float* rstd;
  const float* ln_g; const float* ln_b; const float* tl_initial; const float* premix;
  const float* yv; const float* gres;
  float* h2;                 // fp32, lives in d_out until final gemm overwrites
  const float* Wg[6]; const float* bg[6];
};

// ---- A-operand staging split into prefetch (pure loads) + combine (math) ----
struct AFetch {
  float4 v0, v1, v2, v3, v4;
  float s0, s1, s2, s3;
};

// rows r = t*8 + b (output layout is [T,B,C])
template<int MODE_A>
__device__ __forceinline__ AFetch a_fetch(const GemmArgs& g, int r, int c) {
  AFetch f; f.s0 = f.s1 = f.s2 = f.s3 = 0.f;
  if (MODE_A == 0) {
    f.v0 = *(const float4*)&g.A[r * g.K + c];
  } else if (MODE_A == 1) {
    const int b = r & 7, t = r >> 3;
    f.v0 = *(const float4*)&g.x[(b * T_DIM + t) * C_DIM + c];
    f.s0 = g.mu[r]; f.s1 = g.rstd[r];
    if (t > 0) {
      f.v1 = *(const float4*)&g.x[(b * T_DIM + t - 1) * C_DIM + c];
      f.s2 = g.mu[r - 8]; f.s3 = g.rstd[r - 8];
    } else {
      f.v1 = *(const float4*)&g.tl_initial[c];
    }
    f.v2 = *(const float4*)&g.ln_g[c];
    f.v3 = *(const float4*)&g.ln_b[c];
    f.v4 = *(const float4*)&g.premix[c];
  } else {
    f.v0 = *(const float4*)&g.yv[(r >> 3) * C_DIM + c];
    f.v1 = *(const float4*)&g.h2[r * C_DIM + c];
    f.v2 = *(const float4*)&g.gres[c];
  }
  return f;
}

template<int MODE_A>
__device__ __forceinline__ float4 a_combine(const AFetch& f, int r) {
  if (MODE_A == 0) return f.v0;
  float4 o;
  float* op = (float*)&o;
  const float* xa = (const float*)&f.v0;
  const float* xb = (const float*)&f.v1;
  const float* lg = (const float*)&f.v2;
  const float* lb = (const float*)&f.v3;
  const float* pm = (const float*)&f.v4;
  if (MODE_A == 1) {
    const int t = r >> 3;
    #pragma unroll
    for (int q = 0; q < 4; ++q) {
      float h  = (xa[q] - f.s0) * f.s1 * lg[q] + lb[q];
      float xf = (t == 0) ? xb[q] : (xb[q] - f.s2) * f.s3 * lg[q] + lb[q];
      op[q] = h + (xf - h) * pm[q];
    }
    return o;
  }
  #pragma unroll
  for (int q = 0; q < 4; ++q)
    op[q] = xa[q] + xb[q] * lg[q];     // y + h2*gres
  return o;
}

template<int MODE_B>
__device__ __forceinline__ float4 w_fetch(const GemmArgs& g, int kk, int n0, int tc) {
  if (MODE_B == 1)
    return *(const float4*)&g.Wg[blockIdx.y][kk * 64 + (tc << 2)];
  return *(const float4*)&g.W[kk * g.N + n0 + (tc << 2)];
}

// r15-PROVEN GEMM: register double-buffer prefetch; TL2/gating2 run as
// dim3(128,8)=1024 blocks -> TLP hides W latency.
template<int MODE_A, int MODE_B, int EPI>
__global__ __launch_bounds__(256) void gemm_kernel(GemmArgs g) {
  __shared__ float AsT[16][68];  // [k][m], padded
  __shared__ float Bs[16][64];
  const int m0 = blockIdx.x * 64, n0 = blockIdx.y * 64;
  const int tid = threadIdx.x;
  const int tr = tid >> 4, tc = tid & 15;
  const int ai = tid >> 2, aj = (tid & 3) << 2;
  const float scg = (MODE_B == 1 && blockIdx.y == 1) ? 0.125f : 1.0f;
  float acc[4][4] = {};
  AFetch fa = a_fetch<MODE_A>(g, m0 + ai, aj);
  float4 wv = w_fetch<MODE_B>(g, tr, n0, tc);
  for (int k0 = 0; k0 < g.K; k0 += 16) {
    if (k0) __syncthreads();
    const float4 av = a_combine<MODE_A>(fa, m0 + ai);
    AsT[aj + 0][ai] = av.x;
    AsT[aj + 1][ai] = av.y;
    AsT[aj + 2][ai] = av.z;
    AsT[aj + 3][ai] = av.w;
    *(float4*)&Bs[tr][tc << 2] =
        make_float4(wv.x * scg, wv.y * scg, wv.z * scg, wv.w * scg);
    if (k0 + 16 < g.K) {
      fa = a_fetch<MODE_A>(g, m0 + ai, k0 + 16 + aj);
      wv = w_fetch<MODE_B>(g, k0 + 16 + tr, n0, tc);
    }
    __syncthreads();
    #pragma unroll
    for (int kk = 0; kk < 16; ++kk) {
      const float4 a4 = *(const float4*)&AsT[kk][tr << 2];
      const float4 b4 = *(const float4*)&Bs[kk][tc << 2];
      const float avr[4] = {a4.x, a4.y, a4.z, a4.w};
      const float bvr[4] = {b4.x, b4.y, b4.z, b4.w};
      #pragma unroll
      for (int r_ = 0; r_ < 4; ++r_)
        #pragma unroll
        for (int c_ = 0; c_ < 4; ++c_)
          acc[r_][c_] = fmaf(avr[r_], bvr[c_], acc[r_][c_]);
    }
  }
  #pragma unroll
  for (int r_ = 0; r_ < 4; ++r_) {
    const int rr = m0 + (tr << 2) + r_;
    #pragma unroll
    for (int c_ = 0; c_ < 4; ++c_) {
      const int lc = (tc << 2) + c_;      // column within 64-wide tile
      const int cc = n0 + lc;             // global column
      float v = acc[r_][c_];
      if (MODE_B == 1) v += g.bg[blockIdx.y][lc] * scg;
      else if (g.bias) v += g.bias[cc];
      if (EPI == 0) {
        g.out[rr * g.N + cc] = v;
      } else if (EPI == 1) {
        g.out[rr * g.N + cc] = geluf_(v);
      } else if (EPI == 2) {
        float d = sigmoidf_(v);
        const int b = rr & 7, t = rr >> 3;
        float xv = g.x[(b * T_DIM + t) * C_DIM + cc];
        float h = (xv - g.mu[rr]) * g.rstd[rr] * g.ln_g[cc] + g.ln_b[cc];
        float xf;
        if (t == 0) xf = g.tl_initial[cc];
        else {
          float xp = g.x[(b * T_DIM + t - 1) * C_DIM + cc];
          xf = (xp - g.mu[rr - 8]) * g.rstd[rr - 8] * g.ln_g[cc] + g.ln_b[cc];
        }
        g.h2[rr * C_DIM + cc] = h + (xf - h) * d;
      } else {
        float gate = sigmoidf_(v);
        const int b = rr & 7, t = rr >> 3;
        float res = g.x[(b * T_DIM + t) * C_DIM + cc];
        g.out[rr * C_DIM + cc] = res + g.yv[t * C_DIM + cc] * gate;
      }
    }
  }
}

// ln stats + y0 init folded (2048x256 threads == |y| exactly)
__global__ __launch_bounds__(256) void ln_stats_kernel(const float* __restrict__ x,
                                                       float* __restrict__ mu,
                                                       float* __restrict__ rstd,
                                                       const float* __restrict__ bias,
                                                       float* __restrict__ y) {
  const int gid = blockIdx.x * 256 + threadIdx.x;
  y[gid] = bias[gid & (C_DIM - 1)];
  const int row = blockIdx.x * 4 + (threadIdx.x >> 6);  // r = t*8 + b
  const int lane = threadIdx.x & 63;
  const int b = row & 7, t = row >> 3;
  const float* xr = x + (b * T_DIM + t) * C_DIM;
  float4 v0 = *(const float4*)&xr[lane * 8];
  float4 v1 = *(const float4*)&xr[lane * 8 + 4];
  float s  = v0.x + v0.y + v0.z + v0.w + v1.x + v1.y + v1.z + v1.w;
  float s2 = v0.x*v0.x + v0.y*v0.y + v0.z*v0.z + v0.w*v0.w
           + v1.x*v1.x + v1.y*v1.y + v1.z*v1.z + v1.w*v1.w;
  #pragma unroll
  for (int m = 1; m < 64; m <<= 1) { s += __shfl_xor(s, m); s2 += __shfl_xor(s2, m); }
  if (lane == 0) {
    float mean = s * (1.0f / 512.0f);
    float var = s2 * (1.0f / 512.0f) - mean * mean;
    mu[row] = mean;
    rstd[row] = rsqrtf(var + 1e-5f);
  }
}

// ===== Chunk-parallel scan (CHUNK=16 / NCHUNK=64: half the serial steps in
// phaseA/phaseC with 2x the blocks; combine's serial chain doubles but it is
// the cheapest phase. r21 showed the phases are dependent-chain-bound, not
// load-latency-bound, so parallelism -- not prefetch -- is the lever.) =====
// st_new = st*diag(sg) + (st@a) b^T + c d^T, b prescaled 1/8 at projection.
// PRJ per t: [a|b|c|d|i|sel], 64 each.

// Phase A: per chunk j, P (init I) <- P*M_t ; S (init 0) <- S*M_t + c d^T
// chP written TRANSPOSED for the combine kernel; PRJ read with reg prefetch.
__global__ __launch_bounds__(256) void scan_phaseA(const float* __restrict__ PRJ,
                                                   float* __restrict__ chPT,
                                                   float* __restrict__ chS) {
  const int j = blockIdx.x;
  const int tid = threadIdx.x;
  const int ri = tid >> 4, ci = tid & 15;
  float Pm[4][4], Sm[4][4];
  #pragma unroll
  for (int r = 0; r < 4; ++r)
    #pragma unroll
    for (int c = 0; c < 4; ++c) {
      Pm[r][c] = (ri * 4 + r == ci * 4 + c) ? 1.0f : 0.0f;
      Sm[r][c] = 0.0f;
    }
  const float* base = PRJ + j * CHUNK * 384;
  float4 pa = *(const float4*)&base[      ci * 4];
  float4 pb = *(const float4*)&base[ 64 + ci * 4];
  float4 pc = *(const float4*)&base[128 + ri * 4];
  float4 pd = *(const float4*)&base[192 + ci * 4];
  float4 pi = *(const float4*)&base[256 + ci * 4];
  for (int s = 0; s < CHUNK; ++s) {
    float4 na = pa, nb = pb, nc2 = pc, nd = pd, ni = pi;
    if (s + 1 < CHUNK) {
      const float* b2 = base + (s + 1) * 384;
      na  = *(const float4*)&b2[      ci * 4];
      nb  = *(const float4*)&b2[ 64 + ci * 4];
      nc2 = *(const float4*)&b2[128 + ri * 4];
      nd  = *(const float4*)&b2[192 + ci * 4];
      ni  = *(const float4*)&b2[256 + ci * 4];
    }
    const float sg[4] = {sigmoidf_(pi.x), sigmoidf_(pi.y), sigmoidf_(pi.z), sigmoidf_(pi.w)};
    const float aa[4] = {pa.x, pa.y, pa.z, pa.w};
    const float bb2[4] = {pb.x, pb.y, pb.z, pb.w};
    const float cv[4] = {pc.x, pc.y, pc.z, pc.w};
    const float dd[4] = {pd.x, pd.y, pd.z, pd.w};
    float rp[4], rs[4];
    #pragma unroll
    for (int r = 0; r < 4; ++r) {
      rp[r] = Pm[r][0]*aa[0] + Pm[r][1]*aa[1] + Pm[r][2]*aa[2] + Pm[r][3]*aa[3];
      rs[r] = Sm[r][0]*aa[0] + Sm[r][1]*aa[1] + Sm[r][2]*aa[2] + Sm[r][3]*aa[3];
    }
    #pragma unroll
    for (int m = 1; m <= 8; m <<= 1) {
      #pragma unroll
      for (int r = 0; r < 4; ++r) {
        rp[r] += __shfl_xor(rp[r], m);
        rs[r] += __shfl_xor(rs[r], m);
      }
    }
    #pragma unroll
    for (int r = 0; r < 4; ++r)
      #pragma unroll
      for (int c = 0; c < 4; ++c) {
        Pm[r][c] = Pm[r][c] * sg[c] + rp[r] * bb2[c];
        Sm[r][c] = Sm[r][c] * sg[c] + rs[r] * bb2[c] + cv[r] * dd[c];
      }
    pa = na; pb = nb; pc = nc2; pd = nd; pi = ni;
  }
  float* cpT = chPT + j * 4096;
  float* cs  = chS + j * 4096;
  #pragma unroll
  for (int c = 0; c < 4; ++c)   // transposed: column (ci*4+c)
    *(float4*)&cpT[(ci*4+c)*64 + ri*4] =
        make_float4(Pm[0][c], Pm[1][c], Pm[2][c], Pm[3][c]);
  #pragma unroll
  for (int r = 0; r < 4; ++r)
    *(float4*)&cs[(ri*4+r)*64 + ci*4] = make_float4(Sm[r][0], Sm[r][1], Sm[r][2], Sm[r][3]);
}

// One chunk-step (rv·P + s) with compile-time readlane indices.
__device__ __forceinline__ float cstep(const float4 (&P)[16], float sv, float rv) {
  float p0 = 0.f, p1 = 0.f, p2 = 0.f, p3 = 0.f;
  #pragma unroll
  for (int q = 0; q < 16; ++q) {
    p0 = fmaf(rl_(rv, q * 4 + 0), P[q].x, p0);
    p1 = fmaf(rl_(rv, q * 4 + 1), P[q].y, p1);
    p2 = fmaf(rl_(rv, q * 4 + 2), P[q].z, p2);
    p3 = fmaf(rl_(rv, q * 4 + 3), P[q].w, p3);
  }
  return sv + ((p0 + p1) + (p2 + p3));
}

// Phase B (row-parallel): 64 blocks x 1 wave, one row per wave, lane = column.
// Single register panel (multi-panel pipelines spill to scratch: r12/r13).
__global__ __launch_bounds__(64) void scan_combine(const float* __restrict__ st0,
                                                   const float* __restrict__ chPT,
                                                   const float* __restrict__ chS,
                                                   float* __restrict__ bnd) {
  const int lane = threadIdx.x;          // column c
  const int r = blockIdx.x;              // row 0..63
  float rv = st0[r * 64 + lane];
  const float* basePT = chPT + lane * 64;   // lane's P^T row
  const float* baseS  = chS + r * 64 + lane;
  float* bndRL = bnd + r * 64 + lane;
  for (int j = 0; j < NCHUNK; ++j) {
    float4 P[16];
    const float* pp = basePT + j * 4096;
    #pragma unroll
    for (int q = 0; q < 16; ++q) P[q] = *(const float4*)&pp[q * 4];
    const float sv = baseS[j * 4096];
    bndRL[j * 4096] = rv;
    rv = cstep(P, sv, rv);
  }
}

// Phase C (+ fused y-GEMM): replay chunk with true inbound state; per-t wave
// partials -> LDS; reduce -> osT (padded); in-block o @ Ow with grouped loads.
__global__ __launch_bounds__(256) void scan_phaseC(const float* __restrict__ PRJ,
                                                   const float* __restrict__ bnd,
                                                   const float* __restrict__ Ow,
                                                   float* __restrict__ y) {
  __shared__ float olds[CHUNK][4][64];      // 16 KB
  __shared__ float osT[64][CHUNK + 1];      // padded (4.25 KB)
  const int j = blockIdx.x;
  const int tid = threadIdx.x;
  const int ri = tid >> 4, ci = tid & 15, w = tid >> 6;
  float st[4][4];
  #pragma unroll
  for (int r = 0; r < 4; ++r) {
    const float4 v = *(const float4*)&bnd[j*4096 + (ri*4+r)*64 + ci*4];
    st[r][0] = v.x; st[r][1] = v.y; st[r][2] = v.z; st[r][3] = v.w;
  }
  const float* base = PRJ + j * CHUNK * 384;
  float4 pa = *(const float4*)&base[      ci * 4];
  float4 pb = *(const float4*)&base[ 64 + ci * 4];
  float4 pc = *(const float4*)&base[128 + ri * 4];
  float4 pd = *(const float4*)&base[192 + ci * 4];
  float4 pi = *(const float4*)&base[256 + ci * 4];
  float4 ps = *(const float4*)&base[320 + ri * 4];
  for (int s = 0; s < CHUNK; ++s) {
    float4 na = pa, nb = pb, nc2 = pc, nd = pd, ni = pi, ns = ps;
    if (s + 1 < CHUNK) {
      const float* b2 = base + (s + 1) * 384;
      na  = *(const float4*)&b2[      ci * 4];
      nb  = *(const float4*)&b2[ 64 + ci * 4];
      nc2 = *(const float4*)&b2[128 + ri * 4];
      nd  = *(const float4*)&b2[192 + ci * 4];
      ni  = *(const float4*)&b2[256 + ci * 4];
      ns  = *(const float4*)&b2[320 + ri * 4];
    }
    const float sg[4] = {sigmoidf_(pi.x), sigmoidf_(pi.y), sigmoidf_(pi.z), sigmoidf_(pi.w)};
    const float aa[4] = {pa.x, pa.y, pa.z, pa.w};
    const float bb2[4] = {pb.x, pb.y, pb.z, pb.w};
    const float cv[4] = {pc.x, pc.y, pc.z, pc.w};
    const float dd[4] = {pd.x, pd.y, pd.z, pd.w};
    const float ss[4] = {ps.x, ps.y, ps.z, ps.w};
    float rd[4];
    #pragma unroll
    for (int r = 0; r < 4; ++r)
      rd[r] = st[r][0]*aa[0] + st[r][1]*aa[1] + st[r][2]*aa[2] + st[r][3]*aa[3];
    #pragma unroll
    for (int m = 1; m <= 8; m <<= 1) {
      #pragma unroll
      for (int r = 0; r < 4; ++r) rd[r] += __shfl_xor(rd[r], m);
    }
    float po[4] = {0.f, 0.f, 0.f, 0.f};
    #pragma unroll
    for (int r = 0; r < 4; ++r)
      #pragma unroll
      for (int c = 0; c < 4; ++c) {
        const float nv = st[r][c] * sg[c] + rd[r] * bb2[c] + cv[r] * dd[c];
        st[r][c] = nv;
        po[c] = fmaf(ss[r], nv, po[c]);
      }
    #pragma unroll
    for (int c = 0; c < 4; ++c) {
      po[c] += __shfl_xor(po[c], 16);
      po[c] += __shfl_xor(po[c], 32);
    }
    if ((tid & 48) == 0)
      *(float4*)&olds[s][w][ci * 4] = make_float4(po[0], po[1], po[2], po[3]);
    pa = na; pb = nb; pc = nc2; pd = nd; pi = ni; ps = ns;
  }
  __syncthreads();
  #pragma unroll
  for (int e = 0; e < CHUNK / 4; ++e) {  // cross-wave reduce -> osT[f][t] (padded)
    const int id = tid + 256 * e;
    const int f = id & 63, t = id >> 6;
    osT[f][t] = olds[t][0][f] + olds[t][1][f] + olds[t][2][f] + olds[t][3][f];
  }
  __syncthreads();
  const int c0 = tid << 1;            // 2 output columns per thread
  float2 acc[CHUNK];
  #pragma unroll
  for (int t = 0; t < CHUNK; ++t) acc[t] = make_float2(0.f, 0.f);
  #pragma unroll 1
  for (int fo = 0; fo < 8; ++fo) {    // 8 groups of 8 batched Ow loads
    float2 ow[8];
    #pragma unroll
    for (int q = 0; q < 8; ++q)
      ow[q] = *(const float2*)&Ow[(fo * 8 + q) * C_DIM + c0];
    #pragma unroll
    for (int q = 0; q < 8; ++q) {
      const int f = fo * 8 + q;
      #pragma unroll
      for (int t8 = 0; t8 < CHUNK / 4; ++t8) {
        const float4 ov = *(const float4*)&osT[f][t8 * 4];
        acc[t8*4+0].x = fmaf(ov.x, ow[q].x, acc[t8*4+0].x);
        acc[t8*4+0].y = fmaf(ov.x, ow[q].y, acc[t8*4+0].y);
        acc[t8*4+1].x = fmaf(ov.y, ow[q].x, acc[t8*4+1].x);
        acc[t8*4+1].y = fmaf(ov.y, ow[q].y, acc[t8*4+1].y);
        acc[t8*4+2].x = fmaf(ov.z, ow[q].x, acc[t8*4+2].x);
        acc[t8*4+2].y = fmaf(ov.z, ow[q].y, acc[t8*4+2].y);
        acc[t8*4+3].x = fmaf(ov.w, ow[q].x, acc[t8*4+3].x);
        acc[t8*4+3].y = fmaf(ov.w, ow[q].y, acc[t8*4+3].y);
      }
    }
  }
  #pragma unroll
  for (int t = 0; t < CHUNK; ++t)
    *(float2*)&y[(j * CHUNK + t) * C_DIM + c0] = acc[t];
}

extern "C" void kernel_launch(void* const* d_in, const int* in_sizes, int n_in,
                              void* d_out, int out_size, void* d_ws, size_t ws_size,
                              hipStream_t stream) {
  const float* x       = (const float*)d_in[0];
  const float* ln_g    = (const float*)d_in[1];
  const float* ln_b    = (const float*)d_in[2];
  const float* tl_init = (const float*)d_in[3];
  const float* premix  = (const float*)d_in[4];
  const float* tl_w1   = (const float*)d_in[5];
  const float* tl_b1   = (const float*)d_in[6];
  const float* tl_w2   = (const float*)d_in[7];
  const float* tl_b2   = (const float*)d_in[8];
  const float* bias    = (const float*)d_in[9];
  const float* gres    = (const float*)d_in[10];
  const float* g_w1    = (const float*)d_in[11];
  const float* g_b1    = (const float*)d_in[12];
  const float* g_w2    = (const float*)d_in[13];
  const float* g_b2    = (const float*)d_in[14];
  const float* dn_init = (const float*)d_in[15];
  const float* A_w     = (const float*)d_in[16];
  const float* A_b     = (const float*)d_in[17];
  const float* B_w     = (const float*)d_in[18];
  const float* B_b     = (const float*)d_in[19];
  const float* C_w     = (const float*)d_in[20];
  const float* C_b     = (const float*)d_in[21];
  const float* D_w     = (const float*)d_in[22];
  const float* D_b     = (const float*)d_in[23];
  const float* I_w     = (const float*)d_in[24];
  const float* I_b     = (const float*)d_in[25];
  const float* S_w     = (const float*)d_in[26];
  const float* S_b     = (const float*)d_in[27];
  const float* O_w     = (const float*)d_in[28];

  // ws ~9.0 MB (ws_size >= 27.8 MB: rounds 0-2 ran a 27.8 MB layout cleanly).
  // h2 (fp32, 8192x512 = out_size) lives in d_out until the final gemm
  // overwrites it (only gating gemm1 reads it; same stream).
  float* ws      = (float*)d_ws;
  float* mu      = ws;                  // 8192
  float* rstd    = mu + 8192;           // 8192
  float* hidden1 = rstd + 8192;         // 524288 (8192 x 64; reused by gating)
  float* y       = hidden1 + 524288;    // 524288 (1024 x 512)
  float* PRJ     = y + 524288;          // 393216 (1024 x 384)
  float* chPT    = PRJ + 393216;        // 262144 (64 x 64 x 64, transposed)
  float* chS     = chPT + 262144;       // 262144
  float* bnd     = chS + 262144;        // 262144
  float* h2      = (float*)d_out;       // 4194304 fp32 == full d_out

  ln_stats_kernel<<<2048, 256, 0, stream>>>(x, mu, rstd, bias, y);

  GemmArgs ga = {};
  ga.x = x; ga.mu = mu; ga.rstd = rstd; ga.ln_g = ln_g; ga.ln_b = ln_b;
  ga.tl_initial = tl_init; ga.premix = premix; ga.gres = gres; ga.h2 = h2;

  {  // TokenLerp MLP layer 1: hidden1 = gelu(pm @ tl_w1 + tl_b1)
    GemmArgs g = ga; g.W = tl_w1; g.bias = tl_b1; g.out = hidden1;
    g.M = 8192; g.K = 512; g.N = 64;
    gemm_kernel<1, 0, 1><<<dim3(128, 1), 256, 0, stream>>>(g);
  }
  {  // TokenLerp layer 2 -> h2 (fp32, stored in d_out)
    GemmArgs g = ga; g.A = hidden1; g.W = tl_w2; g.bias = tl_b2;
    g.M = 8192; g.K = 64; g.N = 512;
    gemm_kernel<0, 0, 2><<<dim3(128, 8), 256, 0, stream>>>(g);
  }

  for (int k = 0; k < H_DIM; ++k) {
    {  // fused 6-way projection: PRJ[t, grp*64+f] = y @ {A,B/8,C,D,I,S}_w[k] + bias
      GemmArgs g = ga; g.A = y; g.out = PRJ; g.M = 1024; g.K = 512; g.N = 384;
      const int woff = k * C_DIM * F_DIM, boff = k * F_DIM;
      g.Wg[0] = A_w + woff; g.Wg[1] = B_w + woff; g.Wg[2] = C_w + woff;
      g.Wg[3] = D_w + woff; g.Wg[4] = I_w + woff; g.Wg[5] = S_w + woff;
      g.bg[0] = A_b + boff; g.bg[1] = B_b + boff; g.bg[2] = C_b + boff;
      g.bg[3] = D_b + boff; g.bg[4] = I_b + boff; g.bg[5] = S_b + boff;
      gemm_kernel<0, 1, 0><<<dim3(16, 6), 256, 0, stream>>>(g);
    }
    scan_phaseA<<<NCHUNK, 256, 0, stream>>>(PRJ, chPT, chS);
    scan_combine<<<64, 64, 0, stream>>>(dn_init + k * 4096, chPT, chS, bnd);
    scan_phaseC<<<NCHUNK, 256, 0, stream>>>(PRJ, bnd, O_w + k * F_DIM * C_DIM, y);
  }

  {  // gating layer 1: hidden1 = gelu((y + h2*gres) @ g_w1 + g_b1)
    GemmArgs g = ga; g.yv = y; g.W = g_w1; g.bias = g_b1; g.out = hidden1;
    g.M = 8192; g.K = 512; g.N = 64;
    gemm_kernel<2, 0, 1><<<dim3(128, 1), 256, 0, stream>>>(g);
  }
  {  // gating layer 2 + final output (fp32): out = x^T + y*sigmoid(...)
    GemmArgs g = ga; g.yv = y; g.A = hidden1; g.W = g_w2; g.bias = g_b2;
    g.out = (float*)d_out; g.M = 8192; g.K = 64; g.N = 512;
    gemm_kernel<0, 0, 3><<<dim3(128, 8), 256, 0, stream>>>(g);
  }
}

// Round 23
// 965.239 us; speedup vs baseline: 2.2248x; 1.0223x over previous
//
#include <hip/hip_runtime.h>
#include <hip/hip_bf16.h>

#define T_DIM 1024
#define B_DIM 8
#define C_DIM 512
#define F_DIM 64
#define H_DIM 8
#define CHUNK 32
#define NCHUNK 32

__device__ __forceinline__ float sigmoidf_(float v) { return 1.0f / (1.0f + __expf(-v)); }
__device__ __forceinline__ float geluf_(float v) { return 0.5f * v * (1.0f + erff(v * 0.70710678118654752f)); }
__device__ __forceinline__ float rl_(float v, int l) {
  return __uint_as_float(__builtin_amdgcn_readlane(__float_as_uint(v), l));
}

struct GemmArgs {
  const float* A; const float* W; const float* bias; float* out;
  int M, K, N;
  const float* x; const float* mu; const float* rstd;
  const float* ln_g; const float* ln_b; const float* tl_initial; const float* premix;
  const float* yv; const float* gres;
  float* h2;                 // fp32, lives in d_out until final gemm overwrites
  const float* Wg[6]; const float* bg[6];
};

// ---- A-operand staging split into prefetch (pure loads) + combine (math) ----
struct AFetch {
  float4 v0, v1, v2, v3, v4;
  float s0, s1, s2, s3;
};

// rows r = t*8 + b (output layout is [T,B,C])
template<int MODE_A>
__device__ __forceinline__ AFetch a_fetch(const GemmArgs& g, int r, int c) {
  AFetch f; f.s0 = f.s1 = f.s2 = f.s3 = 0.f;
  if (MODE_A == 0) {
    f.v0 = *(const float4*)&g.A[r * g.K + c];
  } else if (MODE_A == 1) {
    const int b = r & 7, t = r >> 3;
    f.v0 = *(const float4*)&g.x[(b * T_DIM + t) * C_DIM + c];
    f.s0 = g.mu[r]; f.s1 = g.rstd[r];
    if (t > 0) {
      f.v1 = *(const float4*)&g.x[(b * T_DIM + t - 1) * C_DIM + c];
      f.s2 = g.mu[r - 8]; f.s3 = g.rstd[r - 8];
    } else {
      f.v1 = *(const float4*)&g.tl_initial[c];
    }
    f.v2 = *(const float4*)&g.ln_g[c];
    f.v3 = *(const float4*)&g.ln_b[c];
    f.v4 = *(const float4*)&g.premix[c];
  } else {
    f.v0 = *(const float4*)&g.yv[(r >> 3) * C_DIM + c];
    f.v1 = *(const float4*)&g.h2[r * C_DIM + c];
    f.v2 = *(const float4*)&g.gres[c];
  }
  return f;
}

template<int MODE_A>
__device__ __forceinline__ float4 a_combine(const AFetch& f, int r) {
  if (MODE_A == 0) return f.v0;
  float4 o;
  float* op = (float*)&o;
  const float* xa = (const float*)&f.v0;
  const float* xb = (const float*)&f.v1;
  const float* lg = (const float*)&f.v2;
  const float* lb = (const float*)&f.v3;
  const float* pm = (const float*)&f.v4;
  if (MODE_A == 1) {
    const int t = r >> 3;
    #pragma unroll
    for (int q = 0; q < 4; ++q) {
      float h  = (xa[q] - f.s0) * f.s1 * lg[q] + lb[q];
      float xf = (t == 0) ? xb[q] : (xb[q] - f.s2) * f.s3 * lg[q] + lb[q];
      op[q] = h + (xf - h) * pm[q];
    }
    return o;
  }
  #pragma unroll
  for (int q = 0; q < 4; ++q)
    op[q] = xa[q] + xb[q] * lg[q];     // y + h2*gres
  return o;
}

template<int MODE_B>
__device__ __forceinline__ float4 w_fetch(const GemmArgs& g, int kk, int n0, int tc) {
  if (MODE_B == 1)
    return *(const float4*)&g.Wg[blockIdx.y][kk * 64 + (tc << 2)];
  return *(const float4*)&g.W[kk * g.N + n0 + (tc << 2)];
}

// r15-PROVEN GEMM: register double-buffer prefetch; TL2/gating2 run as
// dim3(128,8)=1024 blocks -> TLP hides W latency.
template<int MODE_A, int MODE_B, int EPI>
__global__ __launch_bounds__(256) void gemm_kernel(GemmArgs g) {
  __shared__ float AsT[16][68];  // [k][m], padded
  __shared__ float Bs[16][64];
  const int m0 = blockIdx.x * 64, n0 = blockIdx.y * 64;
  const int tid = threadIdx.x;
  const int tr = tid >> 4, tc = tid & 15;
  const int ai = tid >> 2, aj = (tid & 3) << 2;
  const float scg = (MODE_B == 1 && blockIdx.y == 1) ? 0.125f : 1.0f;
  float acc[4][4] = {};
  AFetch fa = a_fetch<MODE_A>(g, m0 + ai, aj);
  float4 wv = w_fetch<MODE_B>(g, tr, n0, tc);
  for (int k0 = 0; k0 < g.K; k0 += 16) {
    if (k0) __syncthreads();
    const float4 av = a_combine<MODE_A>(fa, m0 + ai);
    AsT[aj + 0][ai] = av.x;
    AsT[aj + 1][ai] = av.y;
    AsT[aj + 2][ai] = av.z;
    AsT[aj + 3][ai] = av.w;
    *(float4*)&Bs[tr][tc << 2] =
        make_float4(wv.x * scg, wv.y * scg, wv.z * scg, wv.w * scg);
    if (k0 + 16 < g.K) {
      fa = a_fetch<MODE_A>(g, m0 + ai, k0 + 16 + aj);
      wv = w_fetch<MODE_B>(g, k0 + 16 + tr, n0, tc);
    }
    __syncthreads();
    #pragma unroll
    for (int kk = 0; kk < 16; ++kk) {
      const float4 a4 = *(const float4*)&AsT[kk][tr << 2];
      const float4 b4 = *(const float4*)&Bs[kk][tc << 2];
      const float avr[4] = {a4.x, a4.y, a4.z, a4.w};
      const float bvr[4] = {b4.x, b4.y, b4.z, b4.w};
      #pragma unroll
      for (int r_ = 0; r_ < 4; ++r_)
        #pragma unroll
        for (int c_ = 0; c_ < 4; ++c_)
          acc[r_][c_] = fmaf(avr[r_], bvr[c_], acc[r_][c_]);
    }
  }
  #pragma unroll
  for (int r_ = 0; r_ < 4; ++r_) {
    const int rr = m0 + (tr << 2) + r_;
    #pragma unroll
    for (int c_ = 0; c_ < 4; ++c_) {
      const int lc = (tc << 2) + c_;      // column within 64-wide tile
      const int cc = n0 + lc;             // global column
      float v = acc[r_][c_];
      if (MODE_B == 1) v += g.bg[blockIdx.y][lc] * scg;
      else if (g.bias) v += g.bias[cc];
      if (EPI == 0) {
        g.out[rr * g.N + cc] = v;
      } else if (EPI == 1) {
        g.out[rr * g.N + cc] = geluf_(v);
      } else if (EPI == 2) {
        float d = sigmoidf_(v);
        const int b = rr & 7, t = rr >> 3;
        float xv = g.x[(b * T_DIM + t) * C_DIM + cc];
        float h = (xv - g.mu[rr]) * g.rstd[rr] * g.ln_g[cc] + g.ln_b[cc];
        float xf;
        if (t == 0) xf = g.tl_initial[cc];
        else {
          float xp = g.x[(b * T_DIM + t - 1) * C_DIM + cc];
          xf = (xp - g.mu[rr - 8]) * g.rstd[rr - 8] * g.ln_g[cc] + g.ln_b[cc];
        }
        g.h2[rr * C_DIM + cc] = h + (xf - h) * d;
      } else {
        float gate = sigmoidf_(v);
        const int b = rr & 7, t = rr >> 3;
        float res = g.x[(b * T_DIM + t) * C_DIM + cc];
        g.out[rr * C_DIM + cc] = res + g.yv[t * C_DIM + cc] * gate;
      }
    }
  }
}

// ln stats + y0 init folded (2048x256 threads == |y| exactly)
__global__ __launch_bounds__(256) void ln_stats_kernel(const float* __restrict__ x,
                                                       float* __restrict__ mu,
                                                       float* __restrict__ rstd,
                                                       const float* __restrict__ bias,
                                                       float* __restrict__ y) {
  const int gid = blockIdx.x * 256 + threadIdx.x;
  y[gid] = bias[gid & (C_DIM - 1)];
  const int row = blockIdx.x * 4 + (threadIdx.x >> 6);  // r = t*8 + b
  const int lane = threadIdx.x & 63;
  const int b = row & 7, t = row >> 3;
  const float* xr = x + (b * T_DIM + t) * C_DIM;
  float4 v0 = *(const float4*)&xr[lane * 8];
  float4 v1 = *(const float4*)&xr[lane * 8 + 4];
  float s  = v0.x + v0.y + v0.z + v0.w + v1.x + v1.y + v1.z + v1.w;
  float s2 = v0.x*v0.x + v0.y*v0.y + v0.z*v0.z + v0.w*v0.w
           + v1.x*v1.x + v1.y*v1.y + v1.z*v1.z + v1.w*v1.w;
  #pragma unroll
  for (int m = 1; m < 64; m <<= 1) { s += __shfl_xor(s, m); s2 += __shfl_xor(s2, m); }
  if (lane == 0) {
    float mean = s * (1.0f / 512.0f);
    float var = s2 * (1.0f / 512.0f) - mean * mean;
    mu[row] = mean;
    rstd[row] = rsqrtf(var + 1e-5f);
  }
}

// ===== Chunk-parallel scan (CHUNK=32: measured optimum -- r22's CHUNK=16
// doubled combine's serial chain for a net loss; r21's prefetch was null
// because the phases are dependent-chain-bound) =====
// st_new = st*diag(sg) + (st@a) b^T + c d^T, b prescaled 1/8 at projection.
// PRJ per t: [a|b|c|d|i|sel], 64 each.

// Phase A: per chunk j, P (init I) <- P*M_t ; S (init 0) <- S*M_t + c d^T
// chP written TRANSPOSED for the combine kernel; PRJ read with reg prefetch.
__global__ __launch_bounds__(256) void scan_phaseA(const float* __restrict__ PRJ,
                                                   float* __restrict__ chPT,
                                                   float* __restrict__ chS) {
  const int j = blockIdx.x;
  const int tid = threadIdx.x;
  const int ri = tid >> 4, ci = tid & 15;
  float Pm[4][4], Sm[4][4];
  #pragma unroll
  for (int r = 0; r < 4; ++r)
    #pragma unroll
    for (int c = 0; c < 4; ++c) {
      Pm[r][c] = (ri * 4 + r == ci * 4 + c) ? 1.0f : 0.0f;
      Sm[r][c] = 0.0f;
    }
  const float* base = PRJ + j * CHUNK * 384;
  float4 pa = *(const float4*)&base[      ci * 4];
  float4 pb = *(const float4*)&base[ 64 + ci * 4];
  float4 pc = *(const float4*)&base[128 + ri * 4];
  float4 pd = *(const float4*)&base[192 + ci * 4];
  float4 pi = *(const float4*)&base[256 + ci * 4];
  for (int s = 0; s < CHUNK; ++s) {
    float4 na = pa, nb = pb, nc2 = pc, nd = pd, ni = pi;
    if (s + 1 < CHUNK) {
      const float* b2 = base + (s + 1) * 384;
      na  = *(const float4*)&b2[      ci * 4];
      nb  = *(const float4*)&b2[ 64 + ci * 4];
      nc2 = *(const float4*)&b2[128 + ri * 4];
      nd  = *(const float4*)&b2[192 + ci * 4];
      ni  = *(const float4*)&b2[256 + ci * 4];
    }
    const float sg[4] = {sigmoidf_(pi.x), sigmoidf_(pi.y), sigmoidf_(pi.z), sigmoidf_(pi.w)};
    const float aa[4] = {pa.x, pa.y, pa.z, pa.w};
    const float bb2[4] = {pb.x, pb.y, pb.z, pb.w};
    const float cv[4] = {pc.x, pc.y, pc.z, pc.w};
    const float dd[4] = {pd.x, pd.y, pd.z, pd.w};
    float rp[4], rs[4];
    #pragma unroll
    for (int r = 0; r < 4; ++r) {
      rp[r] = Pm[r][0]*aa[0] + Pm[r][1]*aa[1] + Pm[r][2]*aa[2] + Pm[r][3]*aa[3];
      rs[r] = Sm[r][0]*aa[0] + Sm[r][1]*aa[1] + Sm[r][2]*aa[2] + Sm[r][3]*aa[3];
    }
    #pragma unroll
    for (int m = 1; m <= 8; m <<= 1) {
      #pragma unroll
      for (int r = 0; r < 4; ++r) {
        rp[r] += __shfl_xor(rp[r], m);
        rs[r] += __shfl_xor(rs[r], m);
      }
    }
    #pragma unroll
    for (int r = 0; r < 4; ++r)
      #pragma unroll
      for (int c = 0; c < 4; ++c) {
        Pm[r][c] = Pm[r][c] * sg[c] + rp[r] * bb2[c];
        Sm[r][c] = Sm[r][c] * sg[c] + rs[r] * bb2[c] + cv[r] * dd[c];
      }
    pa = na; pb = nb; pc = nc2; pd = nd; pi = ni;
  }
  float* cpT = chPT + j * 4096;
  float* cs  = chS + j * 4096;
  #pragma unroll
  for (int c = 0; c < 4; ++c)   // transposed: column (ci*4+c)
    *(float4*)&cpT[(ci*4+c)*64 + ri*4] =
        make_float4(Pm[0][c], Pm[1][c], Pm[2][c], Pm[3][c]);
  #pragma unroll
  for (int r = 0; r < 4; ++r)
    *(float4*)&cs[(ri*4+r)*64 + ci*4] = make_float4(Sm[r][0], Sm[r][1], Sm[r][2], Sm[r][3]);
}

// One chunk-step (rv·P + s) with compile-time readlane indices.
__device__ __forceinline__ float cstep(const float4 (&P)[16], float sv, float rv) {
  float p0 = 0.f, p1 = 0.f, p2 = 0.f, p3 = 0.f;
  #pragma unroll
  for (int q = 0; q < 16; ++q) {
    p0 = fmaf(rl_(rv, q * 4 + 0), P[q].x, p0);
    p1 = fmaf(rl_(rv, q * 4 + 1), P[q].y, p1);
    p2 = fmaf(rl_(rv, q * 4 + 2), P[q].z, p2);
    p3 = fmaf(rl_(rv, q * 4 + 3), P[q].w, p3);
  }
  return sv + ((p0 + p1) + (p2 + p3));
}

// Phase B (row-parallel): 64 blocks x 1 wave, one row per wave, lane = column.
// Single register panel (multi-panel pipelines spill to scratch: r12/r13).
__global__ __launch_bounds__(64) void scan_combine(const float* __restrict__ st0,
                                                   const float* __restrict__ chPT,
                                                   const float* __restrict__ chS,
                                                   float* __restrict__ bnd) {
  const int lane = threadIdx.x;          // column c
  const int r = blockIdx.x;              // row 0..63
  float rv = st0[r * 64 + lane];
  const float* basePT = chPT + lane * 64;   // lane's P^T row
  const float* baseS  = chS + r * 64 + lane;
  float* bndRL = bnd + r * 64 + lane;
  for (int j = 0; j < NCHUNK; ++j) {
    float4 P[16];
    const float* pp = basePT + j * 4096;
    #pragma unroll
    for (int q = 0; q < 16; ++q) P[q] = *(const float4*)&pp[q * 4];
    const float sv = baseS[j * 4096];
    bndRL[j * 4096] = rv;
    rv = cstep(P, sv, rv);
  }
}

// Phase C (+ fused y-GEMM): replay chunk with true inbound state; per-t wave
// partials -> LDS; reduce -> osT (padded); in-block o @ Ow with grouped loads.
__global__ __launch_bounds__(256) void scan_phaseC(const float* __restrict__ PRJ,
                                                   const float* __restrict__ bnd,
                                                   const float* __restrict__ Ow,
                                                   float* __restrict__ y) {
  __shared__ float olds[CHUNK][4][64];      // 32 KB
  __shared__ float osT[64][CHUNK + 1];      // padded (8.25 KB)
  const int j = blockIdx.x;
  const int tid = threadIdx.x;
  const int ri = tid >> 4, ci = tid & 15, w = tid >> 6;
  float st[4][4];
  #pragma unroll
  for (int r = 0; r < 4; ++r) {
    const float4 v = *(const float4*)&bnd[j*4096 + (ri*4+r)*64 + ci*4];
    st[r][0] = v.x; st[r][1] = v.y; st[r][2] = v.z; st[r][3] = v.w;
  }
  const float* base = PRJ + j * CHUNK * 384;
  float4 pa = *(const float4*)&base[      ci * 4];
  float4 pb = *(const float4*)&base[ 64 + ci * 4];
  float4 pc = *(const float4*)&base[128 + ri * 4];
  float4 pd = *(const float4*)&base[192 + ci * 4];
  float4 pi = *(const float4*)&base[256 + ci * 4];
  float4 ps = *(const float4*)&base[320 + ri * 4];
  for (int s = 0; s < CHUNK; ++s) {
    float4 na = pa, nb = pb, nc2 = pc, nd = pd, ni = pi, ns = ps;
    if (s + 1 < CHUNK) {
      const float* b2 = base + (s + 1) * 384;
      na  = *(const float4*)&b2[      ci * 4];
      nb  = *(const float4*)&b2[ 64 + ci * 4];
      nc2 = *(const float4*)&b2[128 + ri * 4];
      nd  = *(const float4*)&b2[192 + ci * 4];
      ni  = *(const float4*)&b2[256 + ci * 4];
      ns  = *(const float4*)&b2[320 + ri * 4];
    }
    const float sg[4] = {sigmoidf_(pi.x), sigmoidf_(pi.y), sigmoidf_(pi.z), sigmoidf_(pi.w)};
    const float aa[4] = {pa.x, pa.y, pa.z, pa.w};
    const float bb2[4] = {pb.x, pb.y, pb.z, pb.w};
    const float cv[4] = {pc.x, pc.y, pc.z, pc.w};
    const float dd[4] = {pd.x, pd.y, pd.z, pd.w};
    const float ss[4] = {ps.x, ps.y, ps.z, ps.w};
    float rd[4];
    #pragma unroll
    for (int r = 0; r < 4; ++r)
      rd[r] = st[r][0]*aa[0] + st[r][1]*aa[1] + st[r][2]*aa[2] + st[r][3]*aa[3];
    #pragma unroll
    for (int m = 1; m <= 8; m <<= 1) {
      #pragma unroll
      for (int r = 0; r < 4; ++r) rd[r] += __shfl_xor(rd[r], m);
    }
    float po[4] = {0.f, 0.f, 0.f, 0.f};
    #pragma unroll
    for (int r = 0; r < 4; ++r)
      #pragma unroll
      for (int c = 0; c < 4; ++c) {
        const float nv = st[r][c] * sg[c] + rd[r] * bb2[c] + cv[r] * dd[c];
        st[r][c] = nv;
        po[c] = fmaf(ss[r], nv, po[c]);
      }
    #pragma unroll
    for (int c = 0; c < 4; ++c) {
      po[c] += __shfl_xor(po[c], 16);
      po[c] += __shfl_xor(po[c], 32);
    }
    if ((tid & 48) == 0)
      *(float4*)&olds[s][w][ci * 4] = make_float4(po[0], po[1], po[2], po[3]);
    pa = na; pb = nb; pc = nc2; pd = nd; pi = ni; ps = ns;
  }
  __syncthreads();
  #pragma unroll
  for (int e = 0; e < 8; ++e) {       // cross-wave reduce -> osT[f][t] (padded)
    const int id = tid + 256 * e;
    const int f = id & 63, t = id >> 6;
    osT[f][t] = olds[t][0][f] + olds[t][1][f] + olds[t][2][f] + olds[t][3][f];
  }
  __syncthreads();
  const int c0 = tid << 1;            // 2 output columns per thread
  float2 acc[CHUNK];
  #pragma unroll
  for (int t = 0; t < CHUNK; ++t) acc[t] = make_float2(0.f, 0.f);
  #pragma unroll 1
  for (int fo = 0; fo < 8; ++fo) {    // 8 groups of 8 batched Ow loads
    float2 ow[8];
    #pragma unroll
    for (int q = 0; q < 8; ++q)
      ow[q] = *(const float2*)&Ow[(fo * 8 + q) * C_DIM + c0];
    #pragma unroll
    for (int q = 0; q < 8; ++q) {
      const int f = fo * 8 + q;
      #pragma unroll
      for (int t8 = 0; t8 < 8; ++t8) {
        const float4 ov = *(const float4*)&osT[f][t8 * 4];
        acc[t8*4+0].x = fmaf(ov.x, ow[q].x, acc[t8*4+0].x);
        acc[t8*4+0].y = fmaf(ov.x, ow[q].y, acc[t8*4+0].y);
        acc[t8*4+1].x = fmaf(ov.y, ow[q].x, acc[t8*4+1].x);
        acc[t8*4+1].y = fmaf(ov.y, ow[q].y, acc[t8*4+1].y);
        acc[t8*4+2].x = fmaf(ov.z, ow[q].x, acc[t8*4+2].x);
        acc[t8*4+2].y = fmaf(ov.z, ow[q].y, acc[t8*4+2].y);
        acc[t8*4+3].x = fmaf(ov.w, ow[q].x, acc[t8*4+3].x);
        acc[t8*4+3].y = fmaf(ov.w, ow[q].y, acc[t8*4+3].y);
      }
    }
  }
  #pragma unroll
  for (int t = 0; t < CHUNK; ++t)
    *(float2*)&y[(j * CHUNK + t) * C_DIM + c0] = acc[t];
}

extern "C" void kernel_launch(void* const* d_in, const int* in_sizes, int n_in,
                              void* d_out, int out_size, void* d_ws, size_t ws_size,
                              hipStream_t stream) {
  const float* x       = (const float*)d_in[0];
  const float* ln_g    = (const float*)d_in[1];
  const float* ln_b    = (const float*)d_in[2];
  const float* tl_init = (const float*)d_in[3];
  const float* premix  = (const float*)d_in[4];
  const float* tl_w1   = (const float*)d_in[5];
  const float* tl_b1   = (const float*)d_in[6];
  const float* tl_w2   = (const float*)d_in[7];
  const float* tl_b2   = (const float*)d_in[8];
  const float* bias    = (const float*)d_in[9];
  const float* gres    = (const float*)d_in[10];
  const float* g_w1    = (const float*)d_in[11];
  const float* g_b1    = (const float*)d_in[12];
  const float* g_w2    = (const float*)d_in[13];
  const float* g_b2    = (const float*)d_in[14];
  const float* dn_init = (const float*)d_in[15];
  const float* A_w     = (const float*)d_in[16];
  const float* A_b     = (const float*)d_in[17];
  const float* B_w     = (const float*)d_in[18];
  const float* B_b     = (const float*)d_in[19];
  const float* C_w     = (const float*)d_in[20];
  const float* C_b     = (const float*)d_in[21];
  const float* D_w     = (const float*)d_in[22];
  const float* D_b     = (const float*)d_in[23];
  const float* I_w     = (const float*)d_in[24];
  const float* I_b     = (const float*)d_in[25];
  const float* S_w     = (const float*)d_in[26];
  const float* S_b     = (const float*)d_in[27];
  const float* O_w     = (const float*)d_in[28];

  // ws ~6.6 MB. h2 (fp32, 8192x512 = out_size) lives in d_out until the final
  // gemm overwrites it (only gating gemm1 reads it; same stream).
  float* ws      = (float*)d_ws;
  float* mu      = ws;                  // 8192
  float* rstd    = mu + 8192;           // 8192
  float* hidden1 = rstd + 8192;         // 524288 (8192 x 64; reused by gating)
  float* y       = hidden1 + 524288;    // 524288 (1024 x 512)
  float* PRJ     = y + 524288;          // 393216 (1024 x 384)
  float* chPT    = PRJ + 393216;        // 131072 (32 x 64 x 64, transposed)
  float* chS     = chPT + 131072;       // 131072
  float* bnd     = chS + 131072;        // 131072
  float* h2      = (float*)d_out;       // 4194304 fp32 == full d_out

  ln_stats_kernel<<<2048, 256, 0, stream>>>(x, mu, rstd, bias, y);

  GemmArgs ga = {};
  ga.x = x; ga.mu = mu; ga.rstd = rstd; ga.ln_g = ln_g; ga.ln_b = ln_b;
  ga.tl_initial = tl_init; ga.premix = premix; ga.gres = gres; ga.h2 = h2;

  {  // TokenLerp MLP layer 1: hidden1 = gelu(pm @ tl_w1 + tl_b1)
    GemmArgs g = ga; g.W = tl_w1; g.bias = tl_b1; g.out = hidden1;
    g.M = 8192; g.K = 512; g.N = 64;
    gemm_kernel<1, 0, 1><<<dim3(128, 1), 256, 0, stream>>>(g);
  }
  {  // TokenLerp layer 2 -> h2 (fp32, stored in d_out)
    GemmArgs g = ga; g.A = hidden1; g.W = tl_w2; g.bias = tl_b2;
    g.M = 8192; g.K = 64; g.N = 512;
    gemm_kernel<0, 0, 2><<<dim3(128, 8), 256, 0, stream>>>(g);
  }

  for (int k = 0; k < H_DIM; ++k) {
    {  // fused 6-way projection: PRJ[t, grp*64+f] = y @ {A,B/8,C,D,I,S}_w[k] + bias
      GemmArgs g = ga; g.A = y; g.out = PRJ; g.M = 1024; g.K = 512; g.N = 384;
      const int woff = k * C_DIM * F_DIM, boff = k * F_DIM;
      g.Wg[0] = A_w + woff; g.Wg[1] = B_w + woff; g.Wg[2] = C_w + woff;
      g.Wg[3] = D_w + woff; g.Wg[4] = I_w + woff; g.Wg[5] = S_w + woff;
      g.bg[0] = A_b + boff; g.bg[1] = B_b + boff; g.bg[2] = C_b + boff;
      g.bg[3] = D_b + boff; g.bg[4] = I_b + boff; g.bg[5] = S_b + boff;
      gemm_kernel<0, 1, 0><<<dim3(16, 6), 256, 0, stream>>>(g);
    }
    scan_phaseA<<<NCHUNK, 256, 0, stream>>>(PRJ, chPT, chS);
    scan_combine<<<64, 64, 0, stream>>>(dn_init + k * 4096, chPT, chS, bnd);
    scan_phaseC<<<NCHUNK, 256, 0, stream>>>(PRJ, bnd, O_w + k * F_DIM * C_DIM, y);
  }

  {  // gating layer 1: hidden1 = gelu((y + h2*gres) @ g_w1 + g_b1)
    GemmArgs g = ga; g.yv = y; g.W = g_w1; g.bias = g_b1; g.out = hidden1;
    g.M = 8192; g.K = 512; g.N = 64;
    gemm_kernel<2, 0, 1><<<dim3(128, 1), 256, 0, stream>>>(g);
  }
  {  // gating layer 2 + final output (fp32): out = x^T + y*sigmoid(...)
    GemmArgs g = ga; g.yv = y; g.A = hidden1; g.W = g_w2; g.bias = g_b2;
    g.out = (float*)d_out; g.M = 8192; g.K = 64; g.N = 512;
    gemm_kernel<0, 0, 3><<<dim3(128, 8), 256, 0, stream>>>(g);
  }
}